// Round 10
// baseline (475.448 us; speedup 1.0000x reference)
//
#include <hip/hip_runtime.h>

typedef unsigned short u16;
typedef __attribute__((ext_vector_type(8))) __bf16 bf8_t;
typedef __attribute__((ext_vector_type(4))) float f4_t;

union bf8u { u16 u[8]; bf8_t v; uint4 q; };

// ---------- bf16 helpers ----------
__device__ __forceinline__ float bf2f(u16 v) {
  return __uint_as_float(((unsigned int)v) << 16);
}
__device__ __forceinline__ u16 f2bf(float f) {
  union { __bf16 h; u16 u; } c;          // gfx950: single v_cvt_pk_bf16_f32 (RNE)
  c.h = (__bf16)f;
  return c.u;
}
__device__ __forceinline__ float bflo(unsigned int w) { return __uint_as_float(w << 16); }
__device__ __forceinline__ float bfhi(unsigned int w) { return __uint_as_float(w & 0xFFFF0000u); }
__device__ __forceinline__ float ldf1(const void* p, size_t i, int isf32) {
  return isf32 ? ((const float*)p)[i] : bf2f(((const u16*)p)[i]);
}
// packed f32x2 -> bf16x2 (RNE), single HW instr
__device__ __forceinline__ unsigned int cvtpk(float lo, float hi) {
  unsigned int w;
  asm("v_cvt_pk_bf16_f32 %0, %1, %2" : "=v"(w) : "v"(lo), "v"(hi));
  return w;
}

// ---------- sizes ----------
#define LQ    2500
#define LQP   2560      /* padded token count for Vt */
#define BB    2
#define CC    256
#define NCC   6
#define HFF   64
#define WFF   176
#define DFF   1024
#define MROWS 5000

// ---------- workspace byte offsets (end < 20.7MB proven-safe) ----------
#define WB_UV   256
#define WB_WQKV 240256
#define WB_WOP  633472
#define WB_WSC  764544
#define WB_WF1  895616
#define WB_WF2  1419904
#define WB_S1   1944192                 /* 2,621,440 each */
#define WB_S2   (WB_S1 + 2621440)
#define WB_S3   (WB_S2 + 2621440)
#define WB_VT   (WB_S3 + 2621440)       /* 512 x 2560 x 2B */
#define WB_H    WB_S2                   /* overlaps S2,S3,VT (dead at FFN time) */

// ============================================================
__global__ void detect_k(const u16* __restrict__ rp, int* __restrict__ flag) {
  int bad = 0;
  for (int i = threadIdx.x; i < 7500; i += 64) {
    float v = bf2f(rp[i]);
    if (!(fabsf(v) < 1e6f)) bad = 1;
  }
  int anybad = __any(bad);
  if (threadIdx.x == 0) flag[0] = anybad ? 1 : 0;   // 1 = f32, 0 = bf16
}

// ============================================================
// prep: vectorized weight convert / Vt pad / uv projection.
//   y in [0,2]: x4 convert; y==3: Vt zero pad; y==4: uv.
// ============================================================
struct WDesc {
  const void* src[3];
  u16* dst[3];
  int n[3];
};
__global__ __launch_bounds__(256) void cvtw_k(WDesc d, u16* __restrict__ vtp,
    const void* __restrict__ refp, const void* __restrict__ intr,
    const void* __restrict__ extr, float* __restrict__ uv,
    const int* __restrict__ flag) {
  const int df = flag[0];
  const int i = blockIdx.y;
  if (i == 4) {                          // uv projection task
    for (int idx = blockIdx.x * 256 + threadIdx.x; idx < BB * NCC * LQ; idx += gridDim.x * 256) {
      const int bc = idx / LQ;
      const int q = idx - bc * LQ;
      float R[3][3], tv[3], Kc[3][3], p[3];
#pragma unroll
      for (int a = 0; a < 3; ++a) {
#pragma unroll
        for (int j = 0; j < 3; ++j) {
          R[a][j] = ldf1(extr, bc*16 + a*4 + j, df);
          Kc[a][j] = ldf1(intr, bc*9 + a*3 + j, df);
        }
        tv[a] = ldf1(extr, bc*16 + a*4 + 3, df);
      }
#pragma unroll
      for (int j = 0; j < 3; ++j) p[j] = ldf1(refp, q*3 + j, df) - tv[j];
      float pc[3];
#pragma unroll
      for (int a = 0; a < 3; ++a) pc[a] = R[0][a]*p[0] + R[1][a]*p[1] + R[2][a]*p[2];
      float im[3];
#pragma unroll
      for (int a = 0; a < 3; ++a) im[a] = Kc[a][0]*pc[0] + Kc[a][1]*pc[1] + Kc[a][2]*pc[2];
      const float z = fmaxf(im[2], 1e-5f);
      uv[(size_t)idx*2 + 0] = im[0] / z - 0.5f;
      uv[(size_t)idx*2 + 1] = im[1] / z - 0.5f;
    }
    return;
  }
  if (i == 3) {                          // Vt zero pad
    const int n = 512 * (LQP - LQ);
    for (int j = blockIdx.x * 256 + threadIdx.x; j < n; j += gridDim.x * 256) {
      const int row = j / (LQP - LQ), col = LQ + j % (LQP - LQ);
      vtp[(size_t)row * LQP + col] = 0;
    }
    return;
  }
  const int n = d.n[i];
  for (int j = blockIdx.x * 256 + threadIdx.x; j < n; j += gridDim.x * 256) {
    if (df) {
      const float4 r = ((const float4*)d.src[i])[j];
      const unsigned int lo = (unsigned int)f2bf(r.x) | ((unsigned int)f2bf(r.y) << 16);
      const unsigned int hi = (unsigned int)f2bf(r.z) | ((unsigned int)f2bf(r.w) << 16);
      ((uint2*)d.dst[i])[j] = make_uint2(lo, hi);
    } else {
      ((uint2*)d.dst[i])[j] = ((const uint2*)d.src[i])[j];
    }
  }
}

// ============================================================
// LDS-tiled transpose-convert for the two FFN weights.
//   dst[n][k] = cvt(src[k][n]).  64x64 tiles.
//   tile[n_idx][k_idx] = src[k0+k_idx][n0+n_idx]:
//     load  (r=k_idx, col=n_idx):  tile[col][r]  <- src coalesced
//     store (n=n_idx, col=k_idx):  tile[n][col]  -> dst coalesced
//   (R9 bug was tile[col][n] here — per-tile transpose dropped.)
// ============================================================
__global__ __launch_bounds__(256) void trans_k(
    const void* __restrict__ s0, u16* __restrict__ d0,
    const void* __restrict__ s1, u16* __restrict__ d1,
    const int* __restrict__ flag)
{
  __shared__ u16 tile[64][66];
  const int df = flag[0];
  const void* src; u16* dst; int Ks, Ns;
  if (blockIdx.y == 0) { src = s0; dst = d0; Ks = 256;  Ns = 1024; }
  else                 { src = s1; dst = d1; Ks = 1024; Ns = 256;  }
  const int ntn = Ns >> 6;
  const int kx = blockIdx.x / ntn, nx = blockIdx.x % ntn;
  const int k0 = kx * 64, n0 = nx * 64;
  const int t = threadIdx.x;
  const int col = t & 63, rq = t >> 6;
#pragma unroll
  for (int i = 0; i < 16; ++i) {
    const int r = i * 4 + rq;
    tile[col][r] = f2bf(ldf1(src, (size_t)(k0 + r) * Ns + n0 + col, df));
  }
  __syncthreads();
#pragma unroll
  for (int i = 0; i < 16; ++i) {
    const int n = i * 4 + rq;
    dst[(size_t)(n0 + n) * Ks + k0 + col] = tile[n][col];
  }
}

// ============================================================
// No-LDS MFMA GEMM, one wave computes 16M x (NT*16)N. (FFN1 only)
// ============================================================
template<int KTPL, int ACT, int NT>
__global__ __launch_bounds__(64) void gemm_nl(
    const u16* __restrict__ Xv, const u16* __restrict__ W,
    const void* __restrict__ bias,
    u16* __restrict__ Y, int M, int N, const int* __restrict__ flag)
{
  const int df = flag[0];
  const int lane = threadIdx.x;
  const int ln15 = lane & 15, l4 = lane >> 4;
  const int m0 = blockIdx.x * 16, n0 = blockIdx.y * (NT * 16);
  const int am = min(m0 + ln15, M - 1);

  f4_t acc[NT];
#pragma unroll
  for (int nt = 0; nt < NT; ++nt) acc[nt] = (f4_t){0.f, 0.f, 0.f, 0.f};

#pragma unroll 8
  for (int k0 = 0; k0 < KTPL; k0 += 32) {
    bf8u a;
    a.q = *(const uint4*)(Xv + (size_t)am * KTPL + k0 + l4 * 8);
#pragma unroll
    for (int nt = 0; nt < NT; ++nt) {
      bf8u b;
      b.q = *(const uint4*)&W[(size_t)(n0 + nt * 16 + ln15) * KTPL + k0 + l4 * 8];
      acc[nt] = __builtin_amdgcn_mfma_f32_16x16x32_bf16(a.v, b.v, acc[nt], 0, 0, 0);
    }
  }
#pragma unroll
  for (int nt = 0; nt < NT; ++nt) {
    const int gn = n0 + nt * 16 + ln15;
    const float bv = ldf1(bias, gn, df);
#pragma unroll
    for (int r = 0; r < 4; ++r) {
      const int gm = m0 + l4 * 4 + r;
      if (gm < M) {
        float x = acc[nt][r] + bv;
        if (ACT) x = 0.5f * x * (1.f + erff(x * 0.70710678118654752f));
        Y[(size_t)gm * N + gn] = f2bf(x);
      }
    }
  }
}

// ============================================================
// Split-K GEMM (N=256) + residual + LayerNorm fused.
//   16 waves = 4 K-slices (ks) x 4 col-groups (wn).  Each wave
//   computes a KT/4 partial of its 16x64 tile -> LDS sP[4][16][260]
//   (pad 260: aligned float4 reads).  One barrier, then wave w
//   reduces + LNs row w fully in-wave (lane = 4 cols, 6-step
//   shuffle).  Wave parallelism x4 vs the 4-wave version.
// ============================================================
template<int KT, int RES, int TOOUT>
__global__ __launch_bounds__(1024) void gemm_ln(
    const u16* __restrict__ Xv, const u16* __restrict__ W,
    const void* __restrict__ bias, const void* __restrict__ resv,
    const void* __restrict__ gw, const void* __restrict__ bw,
    void* __restrict__ Yv, int M, const int* __restrict__ flag)
{
  __shared__ float sP[4][16][260];
  const int df = flag[0];
  const int t = threadIdx.x;
  const int lane = t & 63, w = t >> 6;
  const int ln15 = lane & 15, l4 = lane >> 4;
  const int ks = w >> 2, wn = w & 3;
  const int m0 = blockIdx.x * 16;
  const int am = min(m0 + ln15, M - 1);
  constexpr int KS = KT / 4;
  const int kbase = ks * KS;

  f4_t acc[4];
#pragma unroll
  for (int nt = 0; nt < 4; ++nt) acc[nt] = (f4_t){0.f, 0.f, 0.f, 0.f};

#pragma unroll
  for (int k0 = 0; k0 < KS; k0 += 32) {
    bf8u a;
    a.q = *(const uint4*)(Xv + (size_t)am * KT + kbase + k0 + l4 * 8);
#pragma unroll
    for (int nt = 0; nt < 4; ++nt) {
      bf8u b;
      b.q = *(const uint4*)&W[(size_t)(wn * 64 + nt * 16 + ln15) * KT + kbase + k0 + l4 * 8];
      acc[nt] = __builtin_amdgcn_mfma_f32_16x16x32_bf16(a.v, b.v, acc[nt], 0, 0, 0);
    }
  }
  // ---- write K-slice partials ----
#pragma unroll
  for (int nt = 0; nt < 4; ++nt)
#pragma unroll
    for (int r = 0; r < 4; ++r)
      sP[ks][l4 * 4 + r][wn * 64 + nt * 16 + ln15] = acc[nt][r];
  __syncthreads();
  // ---- phase 2: wave w owns row w; lane owns cols lane*4..+3 ----
  const int gm = m0 + w;
  const int c = lane * 4;
  const float4 x0 = *(const float4*)&sP[0][w][c];
  const float4 x1 = *(const float4*)&sP[1][w][c];
  const float4 x2 = *(const float4*)&sP[2][w][c];
  const float4 x3 = *(const float4*)&sP[3][w][c];
  float xx[4] = { x0.x + x1.x + x2.x + x3.x, x0.y + x1.y + x2.y + x3.y,
                  x0.z + x1.z + x2.z + x3.z, x0.w + x1.w + x2.w + x3.w };
#pragma unroll
  for (int j = 0; j < 4; ++j) xx[j] += ldf1(bias, c + j, df);
  const size_t ri = (size_t)min(gm, M - 1) * CC + c;
  if (RES == 1) {
    const uint2 rr = *(const uint2*)((const u16*)resv + ri);
    xx[0] += bflo(rr.x); xx[1] += bfhi(rr.x);
    xx[2] += bflo(rr.y); xx[3] += bfhi(rr.y);
  } else if (RES == 2) {
    if (df) {
      const float4 rf = *(const float4*)((const float*)resv + ri);
      xx[0] += rf.x; xx[1] += rf.y; xx[2] += rf.z; xx[3] += rf.w;
    } else {
      const uint2 rr = *(const uint2*)((const u16*)resv + ri);
      xx[0] += bflo(rr.x); xx[1] += bfhi(rr.x);
      xx[2] += bflo(rr.y); xx[3] += bfhi(rr.y);
    }
  }
  float s = xx[0] + xx[1] + xx[2] + xx[3];
#pragma unroll
  for (int o = 1; o < 64; o <<= 1) s += __shfl_xor(s, o);
  const float mean = s * 0.00390625f;
  const float d0 = xx[0] - mean, d1 = xx[1] - mean, d2 = xx[2] - mean, d3 = xx[3] - mean;
  float sq = d0*d0 + d1*d1 + d2*d2 + d3*d3;
#pragma unroll
  for (int o = 1; o < 64; o <<= 1) sq += __shfl_xor(sq, o);
  const float rstd = rsqrtf(sq * 0.00390625f + 1e-5f);
  const float g0 = ldf1(gw, c+0, df), g1 = ldf1(gw, c+1, df);
  const float g2 = ldf1(gw, c+2, df), g3 = ldf1(gw, c+3, df);
  const float b0 = ldf1(bw, c+0, df), b1 = ldf1(bw, c+1, df);
  const float b2 = ldf1(bw, c+2, df), b3 = ldf1(bw, c+3, df);
  const float y0 = d0 * rstd * g0 + b0;
  const float y1 = d1 * rstd * g1 + b1;
  const float y2 = d2 * rstd * g2 + b2;
  const float y3 = d3 * rstd * g3 + b3;
  if (gm < M) {
    if (TOOUT && df) {
      *(float4*)((float*)Yv + (size_t)gm * CC + c) = make_float4(y0, y1, y2, y3);
    } else {
      u16* yp = (u16*)Yv + (size_t)gm * CC + c;
      *(uint2*)yp = make_uint2(cvtpk(y0, y1), cvtpk(y2, y3));
    }
  }
}

// ============================================================
// Fused QKV projection (R5-proven): grid (313, 12), one wave/block.
// ============================================================
__global__ __launch_bounds__(64) void gemm_qkv(
    const void* __restrict__ Xq, const void* __restrict__ Xkv,
    const u16* __restrict__ Wqkv, const void* __restrict__ bias,
    u16* __restrict__ Qo, u16* __restrict__ Ko, u16* __restrict__ Vt,
    const int* __restrict__ flag)
{
  const int df = flag[0];
  const int lane = threadIdx.x;
  const int ln15 = lane & 15, l4 = lane >> 4;
  const int which = blockIdx.y >> 2;
  const int n0 = (blockIdx.y & 3) * 64;
  const void* Xv = (which == 0) ? Xq : Xkv;
  const u16* W = Wqkv + (size_t)which * 65536;
  const int m0 = blockIdx.x * 16;
  const int am = min(m0 + ln15, MROWS - 1);

  f4_t acc[4];
#pragma unroll
  for (int nt = 0; nt < 4; ++nt) acc[nt] = (f4_t){0.f, 0.f, 0.f, 0.f};

#pragma unroll 8
  for (int k0 = 0; k0 < CC; k0 += 32) {
    bf8u a;
    if (df) {
      const float* p = (const float*)Xv + (size_t)am * CC + k0 + l4 * 8;
      float4 r0 = *(const float4*)p, r1 = *(const float4*)(p + 4);
      a.u[0]=f2bf(r0.x); a.u[1]=f2bf(r0.y); a.u[2]=f2bf(r0.z); a.u[3]=f2bf(r0.w);
      a.u[4]=f2bf(r1.x); a.u[5]=f2bf(r1.y); a.u[6]=f2bf(r1.z); a.u[7]=f2bf(r1.w);
    } else {
      a.q = *(const uint4*)((const u16*)Xv + (size_t)am * CC + k0 + l4 * 8);
    }
#pragma unroll
    for (int nt = 0; nt < 4; ++nt) {
      bf8u b;
      b.q = *(const uint4*)&W[(size_t)(n0 + nt * 16 + ln15) * CC + k0 + l4 * 8];
      acc[nt] = __builtin_amdgcn_mfma_f32_16x16x32_bf16(a.v, b.v, acc[nt], 0, 0, 0);
    }
  }
#pragma unroll
  for (int nt = 0; nt < 4; ++nt) {
    const int gn = n0 + nt * 16 + ln15;
    const float bv = ldf1(bias, which * 256 + gn, df);
#pragma unroll
    for (int r = 0; r < 4; ++r) {
      const int gm = m0 + l4 * 4 + r;
      if (gm < MROWS) {
        const float x = acc[nt][r] + bv;
        if (which == 2) {
          const int tt = gm >> 1;
          const int tx = tt & 63;
          const int tp = (tx & 35) | ((tx & 12) << 1) | ((tx & 16) >> 2);
          Vt[(size_t)(gn + (gm & 1) * 256) * LQP + ((tt & ~63) | tp)] = f2bf(x);
        } else {
          u16* Y = (which == 0) ? Qo : Ko;
          Y[(size_t)gm * CC + gn] = f2bf(x);
        }
      }
    }
  }
}

// ============================================================
// Split-K flash attention, swapped-operand + register-resident P,
// 32 q per wave (R8-proven: halved load/miss count, -40us).
// ============================================================
#define TPW 10
__global__ __launch_bounds__(256) void attn_mf(
    const u16* __restrict__ Qw, const u16* __restrict__ Kw,
    const u16* __restrict__ Vt, u16* __restrict__ Ow)
{
  __shared__ float sO[4][32][33];                // [wave][q][32 d + pad]
  __shared__ float sM[4][32];
  __shared__ float sL[4][32];
  const int t = threadIdx.x;
  const int lane = t & 63, w = t >> 6;
  const int ln15 = lane & 15, l4 = lane >> 4;
  const int q0 = blockIdx.x * 32;
  const int by = blockIdx.y;           // b*8+h
  const int b = by >> 3, h = by & 7;
  const float SCL2E = 0.25505654481f;  // (1/sqrt(32)) * log2(e)

  bf8u aqA, aqB;
  {
    const int qra = min(q0 + ln15, LQ - 1);
    const int qrb = min(q0 + 16 + ln15, LQ - 1);
    bf8u qr;
    qr.q = *(const uint4*)&Qw[((size_t)qra * BB + b) * CC + h * 32 + l4 * 8];
#pragma unroll
    for (int i = 0; i < 8; ++i) aqA.u[i] = f2bf(bf2f(qr.u[i]) * SCL2E);
    qr.q = *(const uint4*)&Qw[((size_t)qrb * BB + b) * CC + h * 32 + l4 * 8];
#pragma unroll
    for (int i = 0; i < 8; ++i) aqB.u[i] = f2bf(bf2f(qr.u[i]) * SCL2E);
  }

  f4_t oaccA[2], oaccB[2];
  oaccA[0] = (f4_t){0.f,0.f,0.f,0.f}; oaccA[1] = (f4_t){0.f,0.f,0.f,0.f};
  oaccB[0] = (f4_t){0.f,0.f,0.f,0.f}; oaccB[1] = (f4_t){0.f,0.f,0.f,0.f};
  float mA = -1e30f, lA = 0.f;
  float mB = -1e30f, lB = 0.f;

  const int kt0 = w * TPW;
  const u16* Kbase = &Kw[(size_t)b * CC + h * 32 + l4 * 8];
  const u16* Vbase = &Vt[(size_t)(by * 32 + ln15) * LQP + l4 * 8];

  // ---- prefetch K for first tile ----
  bf8u bkn[4];
#pragma unroll
  for (int nt = 0; nt < 4; ++nt)
    bkn[nt].q = *(const uint4*)&Kbase[(size_t)(kt0 * 64 + nt * 16 + ln15) * CC];

  for (int kt = kt0; kt < kt0 + TPW; ++kt) {
    const int kb = kt * 64;
    // ---- Vt loads (consumed last): latency hides under QK+softmax ----
    bf8u av[2][2];
#pragma unroll
    for (int m = 0; m < 2; ++m)
#pragma unroll
      for (int dt = 0; dt < 2; ++dt)
        av[m][dt].q = *(const uint4*)&Vbase[(size_t)(dt * 16) * LQP + kb + m * 32];
    // ---- QK for both q-groups from the shared K fragments ----
    f4_t svA[4], svB[4];
    __builtin_amdgcn_s_setprio(1);
#pragma unroll
    for (int nt = 0; nt < 4; ++nt) {
      f4_t z = (f4_t){0.f,0.f,0.f,0.f};
      svA[nt] = __builtin_amdgcn_mfma_f32_16x16x32_bf16(bkn[nt].v, aqA.v, z, 0, 0, 0);
      f4_t z2 = (f4_t){0.f,0.f,0.f,0.f};
      svB[nt] = __builtin_amdgcn_mfma_f32_16x16x32_bf16(bkn[nt].v, aqB.v, z2, 0, 0, 0);
    }
    __builtin_amdgcn_s_setprio(0);
    // ---- issue next tile's K loads ----
    if (kt + 1 < kt0 + TPW) {
#pragma unroll
      for (int nt = 0; nt < 4; ++nt)
        bkn[nt].q = *(const uint4*)&Kbase[(size_t)(kb + 64 + nt * 16 + ln15) * CC];
    }
    float pA[4][4], pB[4][4];
    if (kb + 64 <= LQ) {
#pragma unroll
      for (int nt = 0; nt < 4; ++nt)
#pragma unroll
        for (int r = 0; r < 4; ++r) { pA[nt][r] = svA[nt][r]; pB[nt][r] = svB[nt][r]; }
    } else {
#pragma unroll
      for (int nt = 0; nt < 4; ++nt)
#pragma unroll
        for (int r = 0; r < 4; ++r) {
          const bool ok = (kb + nt * 16 + l4 * 4 + r < LQ);
          pA[nt][r] = ok ? svA[nt][r] : -1e30f;
          pB[nt][r] = ok ? svB[nt][r] : -1e30f;
        }
    }
    // ---- group A softmax ----
    {
      const float thr = mA + 8.f;
      bool nd = false;
#pragma unroll
      for (int nt = 0; nt < 4; ++nt)
#pragma unroll
        for (int r = 0; r < 4; ++r) nd |= (pA[nt][r] > thr);
      if (__any(nd)) {
        const float x0 = fmaxf(fmaxf(pA[0][0], pA[0][1]), fmaxf(pA[0][2], pA[0][3]));
        const float x1 = fmaxf(fmaxf(pA[1][0], pA[1][1]), fmaxf(pA[1][2], pA[1][3]));
        const float x2 = fmaxf(fmaxf(pA[2][0], pA[2][1]), fmaxf(pA[2][2], pA[2][3]));
        const float x3 = fmaxf(fmaxf(pA[3][0], pA[3][1]), fmaxf(pA[3][2], pA[3][3]));
        float mloc = fmaxf(fmaxf(x0, x1), fmaxf(x2, x3));
        mloc = fmaxf(mloc, __shfl_xor(mloc, 16));
        mloc = fmaxf(mloc, __shfl_xor(mloc, 32));
        const float mn = fmaxf(mA, mloc);
        const float alpha = __builtin_amdgcn_exp2f(mA - mn);
        mA = mn;
        lA *= alpha;
#pragma unroll
        for (int r = 0; r < 4; ++r) { oaccA[0][r] *= alpha; oaccA[1][r] *= alpha; }
      }
      float s = 0.f;
#pragma unroll
      for (int nt = 0; nt < 4; ++nt)
#pragma unroll
        for (int r = 0; r < 4; ++r) {
          const float e = __builtin_amdgcn_exp2f(pA[nt][r] - mA);
          pA[nt][r] = e; s += e;
        }
      lA += s;
    }
    // ---- group B softmax ----
    {
      const float thr = mB + 8.f;
      bool nd = false;
#pragma unroll
      for (int nt = 0; nt < 4; ++nt)
#pragma unroll
        for (int r = 0; r < 4; ++r) nd |= (pB[nt][r] > thr);
      if (__any(nd)) {
        const float x0 = fmaxf(fmaxf(pB[0][0], pB[0][1]), fmaxf(pB[0][2], pB[0][3]));
        const float x1 = fmaxf(fmaxf(pB[1][0], pB[1][1]), fmaxf(pB[1][2], pB[1][3]));
        const float x2 = fmaxf(fmaxf(pB[2][0], pB[2][1]), fmaxf(pB[2][2], pB[2][3]));
        const float x3 = fmaxf(fmaxf(pB[3][0], pB[3][1]), fmaxf(pB[3][2], pB[3][3]));
        float mloc = fmaxf(fmaxf(x0, x1), fmaxf(x2, x3));
        mloc = fmaxf(mloc, __shfl_xor(mloc, 16));
        mloc = fmaxf(mloc, __shfl_xor(mloc, 32));
        const float mn = fmaxf(mB, mloc);
        const float alpha = __builtin_amdgcn_exp2f(mB - mn);
        mB = mn;
        lB *= alpha;
#pragma unroll
        for (int r = 0; r < 4; ++r) { oaccB[0][r] *= alpha; oaccB[1][r] *= alpha; }
      }
      float s = 0.f;
#pragma unroll
      for (int nt = 0; nt < 4; ++nt)
#pragma unroll
        for (int r = 0; r < 4; ++r) {
          const float e = __builtin_amdgcn_exp2f(pB[nt][r] - mB);
          pB[nt][r] = e; s += e;
        }
      lB += s;
    }
    // ---- PV: both groups share av fragments ----
    __builtin_amdgcn_s_setprio(1);
#pragma unroll
    for (int m = 0; m < 2; ++m) {
      bf8u pba, pbb;                   // slot i -> key (2m+(i>>2))*16 + l4*4 + (i&3)
      pba.q = make_uint4(cvtpk(pA[2*m][0], pA[2*m][1]),   cvtpk(pA[2*m][2], pA[2*m][3]),
                         cvtpk(pA[2*m+1][0], pA[2*m+1][1]), cvtpk(pA[2*m+1][2], pA[2*m+1][3]));
      pbb.q = make_uint4(cvtpk(pB[2*m][0], pB[2*m][1]),   cvtpk(pB[2*m][2], pB[2*m][3]),
                         cvtpk(pB[2*m+1][0], pB[2*m+1][1]), cvtpk(pB[2*m+1][2], pB[2*m+1][3]));
#pragma unroll
      for (int dt = 0; dt < 2; ++dt) {
        oaccA[dt] = __builtin_amdgcn_mfma_f32_16x16x32_bf16(av[m][dt].v, pba.v, oaccA[dt], 0, 0, 0);
        oaccB[dt] = __builtin_amdgcn_mfma_f32_16x16x32_bf16(av[m][dt].v, pbb.v, oaccB[dt], 0, 0, 0);
      }
    }
    __builtin_amdgcn_s_setprio(0);
  }
  // ---- reduce l across the 4 l4-lanes of each q (consistent scaling) ----
  lA += __shfl_xor(lA, 16);  lA += __shfl_xor(lA, 32);
  lB += __shfl_xor(lB, 16);  lB += __shfl_xor(lB, 32);
  // ---- write partials, merge in LDS ----
#pragma unroll
  for (int dt = 0; dt < 2; ++dt)
#pragma unroll
    for (int r = 0; r < 4; ++r) {
      sO[w][ln15][dt * 16 + l4 * 4 + r]      = oaccA[dt][r];
      sO[w][16 + ln15][dt * 16 + l4 * 4 + r] = oaccB[dt][r];
    }
  if (l4 == 0) {
    sM[w][ln15] = mA; sL[w][ln15] = lA;
    sM[w][16 + ln15] = mB; sL[w][16 + ln15] = lB;
  }
  __syncthreads();
#pragma unroll
  for (int i = t; i < 1024; i += 256) {
    const int row = i >> 5, col = i & 31;
    const float M = fmaxf(fmaxf(sM[0][row], sM[1][row]), fmaxf(sM[2][row], sM[3][row]));
    float l = 0.f, O = 0.f;
#pragma unroll
    for (int w4 = 0; w4 < 4; ++w4) {
      const float sc = __builtin_amdgcn_exp2f(sM[w4][row] - M);
      l += sc * sL[w4][row];
      O += sc * sO[w4][row][col];
    }
    const int q = q0 + row;
    if (q < LQ)
      Ow[((size_t)q * BB + b) * CC + h * 32 + col] = f2bf(O / l);
  }
}

// ============================================================
// Grid-sample (R0-R4 proven version).
// ============================================================
__global__ __launch_bounds__(256) void samp_k(
    const void* __restrict__ feat, const float* __restrict__ uv,
    u16* __restrict__ S, const int* __restrict__ flag)
{
  const int df = flag[0];
  const int c = blockIdx.x;
  const int b = blockIdx.y / 5;
  const int ch = blockIdx.y % 5;
  const int qend = min((ch + 1) * 500, LQ);
  for (int q = ch * 500 + threadIdx.x; q < qend; q += 256) {
    float acc = 0.f;
#pragma unroll
    for (int cam = 0; cam < NCC; ++cam) {
      const int bc = b * NCC + cam;
      const float x = uv[((size_t)bc * LQ + q) * 2 + 0];
      const float y = uv[((size_t)bc * LQ + q) * 2 + 1];
      const float xf = floorf(x), yf = floorf(y);
      const int x0 = (int)xf, y0 = (int)yf;
      const float wx = x - xf, wy = y - yf;
      const size_t base = ((size_t)bc * CC + c) * (HFF * WFF);
      const bool vx0 = (x0 >= 0) & (x0 < WFF);
      const bool vx1 = (x0 + 1 >= 0) & (x0 + 1 < WFF);
      const bool vy0 = (y0 >= 0) & (y0 < HFF);
      const bool vy1 = (y0 + 1 >= 0) & (y0 + 1 < HFF);
      if (vy0) {
        const size_t rb = base + (size_t)y0 * WFF;
        if (vx0) acc += (1.f - wx) * (1.f - wy) * ldf1(feat, rb + x0, df);
        if (vx1) acc += wx * (1.f - wy) * ldf1(feat, rb + x0 + 1, df);
      }
      if (vy1) {
        const size_t rb = base + (size_t)(y0 + 1) * WFF;
        if (vx0) acc += (1.f - wx) * wy * ldf1(feat, rb + x0, df);
        if (vx1) acc += wx * wy * ldf1(feat, rb + x0 + 1, df);
      }
    }
    S[((size_t)q * BB + b) * CC + c] = f2bf(acc * (1.f / 6.f));
  }
}

// ============================================================
extern "C" void kernel_launch(void* const* d_in, const int* in_sizes, int n_in,
                              void* d_out, int out_size, void* d_ws, size_t ws_size,
                              hipStream_t stream) {
  (void)in_sizes; (void)n_in; (void)out_size; (void)ws_size;
  char* base = (char*)d_ws;
  int* flag = (int*)base;
  float* UV = (float*)(base + WB_UV);
  u16* WQKV = (u16*)(base + WB_WQKV);
  u16* WOP  = (u16*)(base + WB_WOP);
  u16* WSC  = (u16*)(base + WB_WSC);
  u16* WF1  = (u16*)(base + WB_WF1);
  u16* WF2  = (u16*)(base + WB_WF2);
  u16* S1 = (u16*)(base + WB_S1);
  u16* S2 = (u16*)(base + WB_S2);
  u16* S3 = (u16*)(base + WB_S3);
  u16* VT = (u16*)(base + WB_VT);
  u16* H  = (u16*)(base + WB_H);

  detect_k<<<1, 64, 0, stream>>>((const u16*)d_in[3], flag);

  WDesc wd;
  wd.src[0] = d_in[7];  wd.dst[0] = WQKV; wd.n[0] = 49152;
  wd.src[1] = d_in[9];  wd.dst[1] = WOP;  wd.n[1] = 16384;
  wd.src[2] = d_in[13]; wd.dst[2] = WSC;  wd.n[2] = 16384;
  cvtw_k<<<dim3(128, 5), 256, 0, stream>>>(wd, VT, d_in[3], d_in[4], d_in[5], UV, flag);
  trans_k<<<dim3(64, 2), 256, 0, stream>>>(d_in[17], WF1, d_in[19], WF2, flag);

  // Fused QKV projections: Q->S1, K->S2, V->VT (transposed + permuted store)
  gemm_qkv<<<dim3(313, 12), 64, 0, stream>>>(d_in[0], d_in[1], WQKV, d_in[8], S1, S2, VT, flag);

  attn_mf<<<dim3(79, 16), 256, 0, stream>>>(S1, S2, VT, S3);

  // out-proj (+bevq residual) + LN1 -> S2
  gemm_ln<256,2,0><<<313, 1024, 0, stream>>>(S3, WOP, d_in[10], d_in[0], d_in[11], d_in[12], S2, MROWS, flag);

  // sampling -> VT slot (dead after attn)
  samp_k<<<dim3(CC, BB * 5), 256, 0, stream>>>(d_in[2], UV, VT, flag);

  // SCA (+S2 residual) + LN2 -> S1
  gemm_ln<256,1,0><<<313, 1024, 0, stream>>>(VT, WSC, d_in[14], S2, d_in[15], d_in[16], S1, MROWS, flag);

  // FFN: gelu(S1 @ W1 + b1) -> H ; (H @ W2 + b2 + S1) + LN3 -> out
  gemm_nl<256,1,4><<<dim3(313, 16), 64, 0, stream>>>(S1, WF1, d_in[18], H, MROWS, DFF, flag);
  gemm_ln<1024,1,1><<<313, 1024, 0, stream>>>(H, WF2, d_in[20], S1, d_in[21], d_in[22], d_out, MROWS, flag);
}

// Round 11
// 458.621 us; speedup vs baseline: 1.0367x; 1.0367x over previous
//
#include <hip/hip_runtime.h>

typedef unsigned short u16;
typedef __attribute__((ext_vector_type(8))) __bf16 bf8_t;
typedef __attribute__((ext_vector_type(4))) float f4_t;

union bf8u { u16 u[8]; bf8_t v; uint4 q; };

// ---------- bf16 helpers ----------
__device__ __forceinline__ float bf2f(u16 v) {
  return __uint_as_float(((unsigned int)v) << 16);
}
__device__ __forceinline__ u16 f2bf(float f) {
  union { __bf16 h; u16 u; } c;          // gfx950: single v_cvt_pk_bf16_f32 (RNE)
  c.h = (__bf16)f;
  return c.u;
}
__device__ __forceinline__ float bflo(unsigned int w) { return __uint_as_float(w << 16); }
__device__ __forceinline__ float bfhi(unsigned int w) { return __uint_as_float(w & 0xFFFF0000u); }
__device__ __forceinline__ float ldf1(const void* p, size_t i, int isf32) {
  return isf32 ? ((const float*)p)[i] : bf2f(((const u16*)p)[i]);
}
// packed f32x2 -> bf16x2 (RNE), single HW instr
__device__ __forceinline__ unsigned int cvtpk(float lo, float hi) {
  unsigned int w;
  asm("v_cvt_pk_bf16_f32 %0, %1, %2" : "=v"(w) : "v"(lo), "v"(hi));
  return w;
}

// ---------- sizes ----------
#define LQ    2500
#define LQP   2560      /* padded token count for Vt */
#define BB    2
#define CC    256
#define NCC   6
#define HFF   64
#define WFF   176
#define DFF   1024
#define MROWS 5000

// ---------- workspace byte offsets (end < 20.7MB proven-safe) ----------
#define WB_UV   256
#define WB_WQKV 240256
#define WB_WOP  633472
#define WB_WSC  764544
#define WB_WF1  895616
#define WB_WF2  1419904
#define WB_S1   1944192                 /* 2,621,440 each */
#define WB_S2   (WB_S1 + 2621440)
#define WB_S3   (WB_S2 + 2621440)
#define WB_VT   (WB_S3 + 2621440)       /* 512 x 2560 x 2B */
#define WB_H    WB_S2                   /* overlaps S2,S3,VT (dead at FFN time) */

// ============================================================
__global__ void detect_k(const u16* __restrict__ rp, int* __restrict__ flag) {
  int bad = 0;
  for (int i = threadIdx.x; i < 7500; i += 64) {
    float v = bf2f(rp[i]);
    if (!(fabsf(v) < 1e6f)) bad = 1;
  }
  int anybad = __any(bad);
  if (threadIdx.x == 0) flag[0] = anybad ? 1 : 0;   // 1 = f32, 0 = bf16
}

// ============================================================
// prep: vectorized weight convert / Vt pad / uv projection.
//   y in [0,2]: x4 convert; y==3: Vt zero pad; y==4: uv.
// ============================================================
struct WDesc {
  const void* src[3];
  u16* dst[3];
  int n[3];
};
__global__ __launch_bounds__(256) void cvtw_k(WDesc d, u16* __restrict__ vtp,
    const void* __restrict__ refp, const void* __restrict__ intr,
    const void* __restrict__ extr, float* __restrict__ uv,
    const int* __restrict__ flag) {
  const int df = flag[0];
  const int i = blockIdx.y;
  if (i == 4) {                          // uv projection task
    for (int idx = blockIdx.x * 256 + threadIdx.x; idx < BB * NCC * LQ; idx += gridDim.x * 256) {
      const int bc = idx / LQ;
      const int q = idx - bc * LQ;
      float R[3][3], tv[3], Kc[3][3], p[3];
#pragma unroll
      for (int a = 0; a < 3; ++a) {
#pragma unroll
        for (int j = 0; j < 3; ++j) {
          R[a][j] = ldf1(extr, bc*16 + a*4 + j, df);
          Kc[a][j] = ldf1(intr, bc*9 + a*3 + j, df);
        }
        tv[a] = ldf1(extr, bc*16 + a*4 + 3, df);
      }
#pragma unroll
      for (int j = 0; j < 3; ++j) p[j] = ldf1(refp, q*3 + j, df) - tv[j];
      float pc[3];
#pragma unroll
      for (int a = 0; a < 3; ++a) pc[a] = R[0][a]*p[0] + R[1][a]*p[1] + R[2][a]*p[2];
      float im[3];
#pragma unroll
      for (int a = 0; a < 3; ++a) im[a] = Kc[a][0]*pc[0] + Kc[a][1]*pc[1] + Kc[a][2]*pc[2];
      const float z = fmaxf(im[2], 1e-5f);
      uv[(size_t)idx*2 + 0] = im[0] / z - 0.5f;
      uv[(size_t)idx*2 + 1] = im[1] / z - 0.5f;
    }
    return;
  }
  if (i == 3) {                          // Vt zero pad
    const int n = 512 * (LQP - LQ);
    for (int j = blockIdx.x * 256 + threadIdx.x; j < n; j += gridDim.x * 256) {
      const int row = j / (LQP - LQ), col = LQ + j % (LQP - LQ);
      vtp[(size_t)row * LQP + col] = 0;
    }
    return;
  }
  const int n = d.n[i];
  for (int j = blockIdx.x * 256 + threadIdx.x; j < n; j += gridDim.x * 256) {
    if (df) {
      const float4 r = ((const float4*)d.src[i])[j];
      const unsigned int lo = (unsigned int)f2bf(r.x) | ((unsigned int)f2bf(r.y) << 16);
      const unsigned int hi = (unsigned int)f2bf(r.z) | ((unsigned int)f2bf(r.w) << 16);
      ((uint2*)d.dst[i])[j] = make_uint2(lo, hi);
    } else {
      ((uint2*)d.dst[i])[j] = ((const uint2*)d.src[i])[j];
    }
  }
}

// ============================================================
// LDS-tiled transpose-convert for the two FFN weights (R10-proven).
// ============================================================
__global__ __launch_bounds__(256) void trans_k(
    const void* __restrict__ s0, u16* __restrict__ d0,
    const void* __restrict__ s1, u16* __restrict__ d1,
    const int* __restrict__ flag)
{
  __shared__ u16 tile[64][66];
  const int df = flag[0];
  const void* src; u16* dst; int Ks, Ns;
  if (blockIdx.y == 0) { src = s0; dst = d0; Ks = 256;  Ns = 1024; }
  else                 { src = s1; dst = d1; Ks = 1024; Ns = 256;  }
  const int ntn = Ns >> 6;
  const int kx = blockIdx.x / ntn, nx = blockIdx.x % ntn;
  const int k0 = kx * 64, n0 = nx * 64;
  const int t = threadIdx.x;
  const int col = t & 63, rq = t >> 6;
#pragma unroll
  for (int i = 0; i < 16; ++i) {
    const int r = i * 4 + rq;
    tile[col][r] = f2bf(ldf1(src, (size_t)(k0 + r) * Ns + n0 + col, df));
  }
  __syncthreads();
#pragma unroll
  for (int i = 0; i < 16; ++i) {
    const int n = i * 4 + rq;
    dst[(size_t)(n0 + n) * Ks + k0 + col] = tile[n][col];
  }
}

// ============================================================
// No-LDS MFMA GEMM, one wave computes 32M x (NT*16)N: two A-row
// groups share every B fragment (R8 attn lesson: halve load count,
// double MFMA per wave).  FFN1 only.
// ============================================================
template<int KTPL, int ACT, int NT>
__global__ __launch_bounds__(64) void gemm_nl(
    const u16* __restrict__ Xv, const u16* __restrict__ W,
    const void* __restrict__ bias,
    u16* __restrict__ Y, int M, int N, const int* __restrict__ flag)
{
  const int df = flag[0];
  const int lane = threadIdx.x;
  const int ln15 = lane & 15, l4 = lane >> 4;
  const int m0 = blockIdx.x * 32, n0 = blockIdx.y * (NT * 16);
  const int am0 = min(m0 + ln15, M - 1);
  const int am1 = min(m0 + 16 + ln15, M - 1);

  f4_t acc[2][NT];
#pragma unroll
  for (int g = 0; g < 2; ++g)
#pragma unroll
    for (int nt = 0; nt < NT; ++nt) acc[g][nt] = (f4_t){0.f, 0.f, 0.f, 0.f};

#pragma unroll 8
  for (int k0 = 0; k0 < KTPL; k0 += 32) {
    bf8u a0, a1;
    a0.q = *(const uint4*)(Xv + (size_t)am0 * KTPL + k0 + l4 * 8);
    a1.q = *(const uint4*)(Xv + (size_t)am1 * KTPL + k0 + l4 * 8);
#pragma unroll
    for (int nt = 0; nt < NT; ++nt) {
      bf8u b;
      b.q = *(const uint4*)&W[(size_t)(n0 + nt * 16 + ln15) * KTPL + k0 + l4 * 8];
      acc[0][nt] = __builtin_amdgcn_mfma_f32_16x16x32_bf16(a0.v, b.v, acc[0][nt], 0, 0, 0);
      acc[1][nt] = __builtin_amdgcn_mfma_f32_16x16x32_bf16(a1.v, b.v, acc[1][nt], 0, 0, 0);
    }
  }
#pragma unroll
  for (int g = 0; g < 2; ++g) {
#pragma unroll
    for (int nt = 0; nt < NT; ++nt) {
      const int gn = n0 + nt * 16 + ln15;
      const float bv = ldf1(bias, gn, df);
#pragma unroll
      for (int r = 0; r < 4; ++r) {
        const int gm = m0 + g * 16 + l4 * 4 + r;
        if (gm < M) {
          float x = acc[g][nt][r] + bv;
          if (ACT) x = 0.5f * x * (1.f + erff(x * 0.70710678118654752f));
          Y[(size_t)gm * N + gn] = f2bf(x);
        }
      }
    }
  }
}

// ============================================================
// GEMM (N=256) + residual + LayerNorm fused (R8-proven 4-wave).
// ============================================================
template<int KT, int RES, int TOOUT>
__global__ __launch_bounds__(256) void gemm_ln(
    const u16* __restrict__ Xv, const u16* __restrict__ W,
    const void* __restrict__ bias, const void* __restrict__ resv,
    const void* __restrict__ gw, const void* __restrict__ bw,
    void* __restrict__ Yv, int M, const int* __restrict__ flag)
{
  __shared__ float sR[4][16];
  const int df = flag[0];
  const int t = threadIdx.x;
  const int lane = t & 63, wn = t >> 6;
  const int ln15 = lane & 15, l4 = lane >> 4;
  const int m0 = blockIdx.x * 16;
  const int am = min(m0 + ln15, M - 1);

  f4_t acc[4];
#pragma unroll
  for (int nt = 0; nt < 4; ++nt) acc[nt] = (f4_t){0.f, 0.f, 0.f, 0.f};

#pragma unroll 8
  for (int k0 = 0; k0 < KT; k0 += 32) {
    bf8u a;
    a.q = *(const uint4*)(Xv + (size_t)am * KT + k0 + l4 * 8);
#pragma unroll
    for (int nt = 0; nt < 4; ++nt) {
      bf8u b;
      b.q = *(const uint4*)&W[(size_t)(wn * 64 + nt * 16 + ln15) * KT + k0 + l4 * 8];
      acc[nt] = __builtin_amdgcn_mfma_f32_16x16x32_bf16(a.v, b.v, acc[nt], 0, 0, 0);
    }
  }
  // ---- x = acc + bias + residual ----
  float x[4][4];
#pragma unroll
  for (int nt = 0; nt < 4; ++nt) {
    const int gn = wn * 64 + nt * 16 + ln15;
    const float bv = ldf1(bias, gn, df);
#pragma unroll
    for (int r = 0; r < 4; ++r) {
      const int gm = m0 + l4 * 4 + r;
      float xx = acc[nt][r] + bv;
      const size_t ri = (size_t)min(gm, M - 1) * CC + gn;
      if (RES == 1)      xx += bf2f(((const u16*)resv)[ri]);
      else if (RES == 2) xx += ldf1(resv, ri, df);
      x[nt][r] = xx;
    }
  }
  // ---- pass 1: row mean ----
  float ps[4];
#pragma unroll
  for (int r = 0; r < 4; ++r) {
    ps[r] = x[0][r] + x[1][r] + x[2][r] + x[3][r];
#pragma unroll
    for (int o = 1; o < 16; o <<= 1) ps[r] += __shfl_xor(ps[r], o);
  }
  if (ln15 == 0) {
#pragma unroll
    for (int r = 0; r < 4; ++r) sR[wn][l4 * 4 + r] = ps[r];
  }
  __syncthreads();
  float mean[4];
#pragma unroll
  for (int r = 0; r < 4; ++r) {
    const int row = l4 * 4 + r;
    mean[r] = (sR[0][row] + sR[1][row] + sR[2][row] + sR[3][row]) * 0.00390625f;
  }
  __syncthreads();
  // ---- pass 2: row variance ----
  float pq[4];
#pragma unroll
  for (int r = 0; r < 4; ++r) {
    float d0 = x[0][r] - mean[r], d1 = x[1][r] - mean[r];
    float d2 = x[2][r] - mean[r], d3 = x[3][r] - mean[r];
    pq[r] = d0*d0 + d1*d1 + d2*d2 + d3*d3;
#pragma unroll
    for (int o = 1; o < 16; o <<= 1) pq[r] += __shfl_xor(pq[r], o);
  }
  if (ln15 == 0) {
#pragma unroll
    for (int r = 0; r < 4; ++r) sR[wn][l4 * 4 + r] = pq[r];
  }
  __syncthreads();
  float rstd[4];
#pragma unroll
  for (int r = 0; r < 4; ++r) {
    const int row = l4 * 4 + r;
    const float v = (sR[0][row] + sR[1][row] + sR[2][row] + sR[3][row]) * 0.00390625f;
    rstd[r] = rsqrtf(v + 1e-5f);
  }
  // ---- normalize + write ----
#pragma unroll
  for (int nt = 0; nt < 4; ++nt) {
    const int gn = wn * 64 + nt * 16 + ln15;
    const float g = ldf1(gw, gn, df);
    const float be = ldf1(bw, gn, df);
#pragma unroll
    for (int r = 0; r < 4; ++r) {
      const int gm = m0 + l4 * 4 + r;
      if (gm < M) {
        const float y = (x[nt][r] - mean[r]) * rstd[r] * g + be;
        if (TOOUT && df) ((float*)Yv)[(size_t)gm * CC + gn] = y;
        else             ((u16*)Yv)[(size_t)gm * CC + gn] = f2bf(y);
      }
    }
  }
}

// ============================================================
// Fused QKV projection, 32 M-rows per wave (shared B fragments).
// grid (157, 12): y>>2 = {Q,K,V}, y&3 = 64-col tile.
// ============================================================
__global__ __launch_bounds__(64) void gemm_qkv(
    const void* __restrict__ Xq, const void* __restrict__ Xkv,
    const u16* __restrict__ Wqkv, const void* __restrict__ bias,
    u16* __restrict__ Qo, u16* __restrict__ Ko, u16* __restrict__ Vt,
    const int* __restrict__ flag)
{
  const int df = flag[0];
  const int lane = threadIdx.x;
  const int ln15 = lane & 15, l4 = lane >> 4;
  const int which = blockIdx.y >> 2;
  const int n0 = (blockIdx.y & 3) * 64;
  const void* Xv = (which == 0) ? Xq : Xkv;
  const u16* W = Wqkv + (size_t)which * 65536;
  const int m0 = blockIdx.x * 32;
  const int am0 = min(m0 + ln15, MROWS - 1);
  const int am1 = min(m0 + 16 + ln15, MROWS - 1);

  f4_t acc[2][4];
#pragma unroll
  for (int g = 0; g < 2; ++g)
#pragma unroll
    for (int nt = 0; nt < 4; ++nt) acc[g][nt] = (f4_t){0.f, 0.f, 0.f, 0.f};

#pragma unroll 8
  for (int k0 = 0; k0 < CC; k0 += 32) {
    bf8u a0, a1;
    if (df) {
      const float* p0 = (const float*)Xv + (size_t)am0 * CC + k0 + l4 * 8;
      float4 r0 = *(const float4*)p0, r1 = *(const float4*)(p0 + 4);
      a0.u[0]=f2bf(r0.x); a0.u[1]=f2bf(r0.y); a0.u[2]=f2bf(r0.z); a0.u[3]=f2bf(r0.w);
      a0.u[4]=f2bf(r1.x); a0.u[5]=f2bf(r1.y); a0.u[6]=f2bf(r1.z); a0.u[7]=f2bf(r1.w);
      const float* p1 = (const float*)Xv + (size_t)am1 * CC + k0 + l4 * 8;
      float4 r2 = *(const float4*)p1, r3 = *(const float4*)(p1 + 4);
      a1.u[0]=f2bf(r2.x); a1.u[1]=f2bf(r2.y); a1.u[2]=f2bf(r2.z); a1.u[3]=f2bf(r2.w);
      a1.u[4]=f2bf(r3.x); a1.u[5]=f2bf(r3.y); a1.u[6]=f2bf(r3.z); a1.u[7]=f2bf(r3.w);
    } else {
      a0.q = *(const uint4*)((const u16*)Xv + (size_t)am0 * CC + k0 + l4 * 8);
      a1.q = *(const uint4*)((const u16*)Xv + (size_t)am1 * CC + k0 + l4 * 8);
    }
#pragma unroll
    for (int nt = 0; nt < 4; ++nt) {
      bf8u b;
      b.q = *(const uint4*)&W[(size_t)(n0 + nt * 16 + ln15) * CC + k0 + l4 * 8];
      acc[0][nt] = __builtin_amdgcn_mfma_f32_16x16x32_bf16(a0.v, b.v, acc[0][nt], 0, 0, 0);
      acc[1][nt] = __builtin_amdgcn_mfma_f32_16x16x32_bf16(a1.v, b.v, acc[1][nt], 0, 0, 0);
    }
  }
#pragma unroll
  for (int g = 0; g < 2; ++g) {
#pragma unroll
    for (int nt = 0; nt < 4; ++nt) {
      const int gn = n0 + nt * 16 + ln15;
      const float bv = ldf1(bias, which * 256 + gn, df);
#pragma unroll
      for (int r = 0; r < 4; ++r) {
        const int gm = m0 + g * 16 + l4 * 4 + r;
        if (gm < MROWS) {
          const float x = acc[g][nt][r] + bv;
          if (which == 2) {
            const int tt = gm >> 1;
            const int tx = tt & 63;
            const int tp = (tx & 35) | ((tx & 12) << 1) | ((tx & 16) >> 2);
            Vt[(size_t)(gn + (gm & 1) * 256) * LQP + ((tt & ~63) | tp)] = f2bf(x);
          } else {
            u16* Y = (which == 0) ? Qo : Ko;
            Y[(size_t)gm * CC + gn] = f2bf(x);
          }
        }
      }
    }
  }
}

// ============================================================
// Split-K flash attention, swapped-operand + register-resident P,
// 32 q per wave (R8-proven: halved load/miss count, -40us).
// ============================================================
#define TPW 10
__global__ __launch_bounds__(256) void attn_mf(
    const u16* __restrict__ Qw, const u16* __restrict__ Kw,
    const u16* __restrict__ Vt, u16* __restrict__ Ow)
{
  __shared__ float sO[4][32][33];                // [wave][q][32 d + pad]
  __shared__ float sM[4][32];
  __shared__ float sL[4][32];
  const int t = threadIdx.x;
  const int lane = t & 63, w = t >> 6;
  const int ln15 = lane & 15, l4 = lane >> 4;
  const int q0 = blockIdx.x * 32;
  const int by = blockIdx.y;           // b*8+h
  const int b = by >> 3, h = by & 7;
  const float SCL2E = 0.25505654481f;  // (1/sqrt(32)) * log2(e)

  bf8u aqA, aqB;
  {
    const int qra = min(q0 + ln15, LQ - 1);
    const int qrb = min(q0 + 16 + ln15, LQ - 1);
    bf8u qr;
    qr.q = *(const uint4*)&Qw[((size_t)qra * BB + b) * CC + h * 32 + l4 * 8];
#pragma unroll
    for (int i = 0; i < 8; ++i) aqA.u[i] = f2bf(bf2f(qr.u[i]) * SCL2E);
    qr.q = *(const uint4*)&Qw[((size_t)qrb * BB + b) * CC + h * 32 + l4 * 8];
#pragma unroll
    for (int i = 0; i < 8; ++i) aqB.u[i] = f2bf(bf2f(qr.u[i]) * SCL2E);
  }

  f4_t oaccA[2], oaccB[2];
  oaccA[0] = (f4_t){0.f,0.f,0.f,0.f}; oaccA[1] = (f4_t){0.f,0.f,0.f,0.f};
  oaccB[0] = (f4_t){0.f,0.f,0.f,0.f}; oaccB[1] = (f4_t){0.f,0.f,0.f,0.f};
  float mA = -1e30f, lA = 0.f;
  float mB = -1e30f, lB = 0.f;

  const int kt0 = w * TPW;
  const u16* Kbase = &Kw[(size_t)b * CC + h * 32 + l4 * 8];
  const u16* Vbase = &Vt[(size_t)(by * 32 + ln15) * LQP + l4 * 8];

  // ---- prefetch K for first tile ----
  bf8u bkn[4];
#pragma unroll
  for (int nt = 0; nt < 4; ++nt)
    bkn[nt].q = *(const uint4*)&Kbase[(size_t)(kt0 * 64 + nt * 16 + ln15) * CC];

  for (int kt = kt0; kt < kt0 + TPW; ++kt) {
    const int kb = kt * 64;
    // ---- Vt loads (consumed last): latency hides under QK+softmax ----
    bf8u av[2][2];
#pragma unroll
    for (int m = 0; m < 2; ++m)
#pragma unroll
      for (int dt = 0; dt < 2; ++dt)
        av[m][dt].q = *(const uint4*)&Vbase[(size_t)(dt * 16) * LQP + kb + m * 32];
    // ---- QK for both q-groups from the shared K fragments ----
    f4_t svA[4], svB[4];
    __builtin_amdgcn_s_setprio(1);
#pragma unroll
    for (int nt = 0; nt < 4; ++nt) {
      f4_t z = (f4_t){0.f,0.f,0.f,0.f};
      svA[nt] = __builtin_amdgcn_mfma_f32_16x16x32_bf16(bkn[nt].v, aqA.v, z, 0, 0, 0);
      f4_t z2 = (f4_t){0.f,0.f,0.f,0.f};
      svB[nt] = __builtin_amdgcn_mfma_f32_16x16x32_bf16(bkn[nt].v, aqB.v, z2, 0, 0, 0);
    }
    __builtin_amdgcn_s_setprio(0);
    // ---- issue next tile's K loads ----
    if (kt + 1 < kt0 + TPW) {
#pragma unroll
      for (int nt = 0; nt < 4; ++nt)
        bkn[nt].q = *(const uint4*)&Kbase[(size_t)(kb + 64 + nt * 16 + ln15) * CC];
    }
    float pA[4][4], pB[4][4];
    if (kb + 64 <= LQ) {
#pragma unroll
      for (int nt = 0; nt < 4; ++nt)
#pragma unroll
        for (int r = 0; r < 4; ++r) { pA[nt][r] = svA[nt][r]; pB[nt][r] = svB[nt][r]; }
    } else {
#pragma unroll
      for (int nt = 0; nt < 4; ++nt)
#pragma unroll
        for (int r = 0; r < 4; ++r) {
          const bool ok = (kb + nt * 16 + l4 * 4 + r < LQ);
          pA[nt][r] = ok ? svA[nt][r] : -1e30f;
          pB[nt][r] = ok ? svB[nt][r] : -1e30f;
        }
    }
    // ---- group A softmax ----
    {
      const float thr = mA + 8.f;
      bool nd = false;
#pragma unroll
      for (int nt = 0; nt < 4; ++nt)
#pragma unroll
        for (int r = 0; r < 4; ++r) nd |= (pA[nt][r] > thr);
      if (__any(nd)) {
        const float x0 = fmaxf(fmaxf(pA[0][0], pA[0][1]), fmaxf(pA[0][2], pA[0][3]));
        const float x1 = fmaxf(fmaxf(pA[1][0], pA[1][1]), fmaxf(pA[1][2], pA[1][3]));
        const float x2 = fmaxf(fmaxf(pA[2][0], pA[2][1]), fmaxf(pA[2][2], pA[2][3]));
        const float x3 = fmaxf(fmaxf(pA[3][0], pA[3][1]), fmaxf(pA[3][2], pA[3][3]));
        float mloc = fmaxf(fmaxf(x0, x1), fmaxf(x2, x3));
        mloc = fmaxf(mloc, __shfl_xor(mloc, 16));
        mloc = fmaxf(mloc, __shfl_xor(mloc, 32));
        const float mn = fmaxf(mA, mloc);
        const float alpha = __builtin_amdgcn_exp2f(mA - mn);
        mA = mn;
        lA *= alpha;
#pragma unroll
        for (int r = 0; r < 4; ++r) { oaccA[0][r] *= alpha; oaccA[1][r] *= alpha; }
      }
      float s = 0.f;
#pragma unroll
      for (int nt = 0; nt < 4; ++nt)
#pragma unroll
        for (int r = 0; r < 4; ++r) {
          const float e = __builtin_amdgcn_exp2f(pA[nt][r] - mA);
          pA[nt][r] = e; s += e;
        }
      lA += s;
    }
    // ---- group B softmax ----
    {
      const float thr = mB + 8.f;
      bool nd = false;
#pragma unroll
      for (int nt = 0; nt < 4; ++nt)
#pragma unroll
        for (int r = 0; r < 4; ++r) nd |= (pB[nt][r] > thr);
      if (__any(nd)) {
        const float x0 = fmaxf(fmaxf(pB[0][0], pB[0][1]), fmaxf(pB[0][2], pB[0][3]));
        const float x1 = fmaxf(fmaxf(pB[1][0], pB[1][1]), fmaxf(pB[1][2], pB[1][3]));
        const float x2 = fmaxf(fmaxf(pB[2][0], pB[2][1]), fmaxf(pB[2][2], pB[2][3]));
        const float x3 = fmaxf(fmaxf(pB[3][0], pB[3][1]), fmaxf(pB[3][2], pB[3][3]));
        float mloc = fmaxf(fmaxf(x0, x1), fmaxf(x2, x3));
        mloc = fmaxf(mloc, __shfl_xor(mloc, 16));
        mloc = fmaxf(mloc, __shfl_xor(mloc, 32));
        const float mn = fmaxf(mB, mloc);
        const float alpha = __builtin_amdgcn_exp2f(mB - mn);
        mB = mn;
        lB *= alpha;
#pragma unroll
        for (int r = 0; r < 4; ++r) { oaccB[0][r] *= alpha; oaccB[1][r] *= alpha; }
      }
      float s = 0.f;
#pragma unroll
      for (int nt = 0; nt < 4; ++nt)
#pragma unroll
        for (int r = 0; r < 4; ++r) {
          const float e = __builtin_amdgcn_exp2f(pB[nt][r] - mB);
          pB[nt][r] = e; s += e;
        }
      lB += s;
    }
    // ---- PV: both groups share av fragments ----
    __builtin_amdgcn_s_setprio(1);
#pragma unroll
    for (int m = 0; m < 2; ++m) {
      bf8u pba, pbb;                   // slot i -> key (2m+(i>>2))*16 + l4*4 + (i&3)
      pba.q = make_uint4(cvtpk(pA[2*m][0], pA[2*m][1]),   cvtpk(pA[2*m][2], pA[2*m][3]),
                         cvtpk(pA[2*m+1][0], pA[2*m+1][1]), cvtpk(pA[2*m+1][2], pA[2*m+1][3]));
      pbb.q = make_uint4(cvtpk(pB[2*m][0], pB[2*m][1]),   cvtpk(pB[2*m][2], pB[2*m][3]),
                         cvtpk(pB[2*m+1][0], pB[2*m+1][1]), cvtpk(pB[2*m+1][2], pB[2*m+1][3]));
#pragma unroll
      for (int dt = 0; dt < 2; ++dt) {
        oaccA[dt] = __builtin_amdgcn_mfma_f32_16x16x32_bf16(av[m][dt].v, pba.v, oaccA[dt], 0, 0, 0);
        oaccB[dt] = __builtin_amdgcn_mfma_f32_16x16x32_bf16(av[m][dt].v, pbb.v, oaccB[dt], 0, 0, 0);
      }
    }
    __builtin_amdgcn_s_setprio(0);
  }
  // ---- reduce l across the 4 l4-lanes of each q (consistent scaling) ----
  lA += __shfl_xor(lA, 16);  lA += __shfl_xor(lA, 32);
  lB += __shfl_xor(lB, 16);  lB += __shfl_xor(lB, 32);
  // ---- write partials, merge in LDS ----
#pragma unroll
  for (int dt = 0; dt < 2; ++dt)
#pragma unroll
    for (int r = 0; r < 4; ++r) {
      sO[w][ln15][dt * 16 + l4 * 4 + r]      = oaccA[dt][r];
      sO[w][16 + ln15][dt * 16 + l4 * 4 + r] = oaccB[dt][r];
    }
  if (l4 == 0) {
    sM[w][ln15] = mA; sL[w][ln15] = lA;
    sM[w][16 + ln15] = mB; sL[w][16 + ln15] = lB;
  }
  __syncthreads();
#pragma unroll
  for (int i = t; i < 1024; i += 256) {
    const int row = i >> 5, col = i & 31;
    const float M = fmaxf(fmaxf(sM[0][row], sM[1][row]), fmaxf(sM[2][row], sM[3][row]));
    float l = 0.f, O = 0.f;
#pragma unroll
    for (int w4 = 0; w4 < 4; ++w4) {
      const float sc = __builtin_amdgcn_exp2f(sM[w4][row] - M);
      l += sc * sL[w4][row];
      O += sc * sO[w4][row][col];
    }
    const int q = q0 + row;
    if (q < LQ)
      Ow[((size_t)q * BB + b) * CC + h * 32 + col] = f2bf(O / l);
  }
}

// ============================================================
// Grid-sample (R0-R4 proven version).
// ============================================================
__global__ __launch_bounds__(256) void samp_k(
    const void* __restrict__ feat, const float* __restrict__ uv,
    u16* __restrict__ S, const int* __restrict__ flag)
{
  const int df = flag[0];
  const int c = blockIdx.x;
  const int b = blockIdx.y / 5;
  const int ch = blockIdx.y % 5;
  const int qend = min((ch + 1) * 500, LQ);
  for (int q = ch * 500 + threadIdx.x; q < qend; q += 256) {
    float acc = 0.f;
#pragma unroll
    for (int cam = 0; cam < NCC; ++cam) {
      const int bc = b * NCC + cam;
      const float x = uv[((size_t)bc * LQ + q) * 2 + 0];
      const float y = uv[((size_t)bc * LQ + q) * 2 + 1];
      const float xf = floorf(x), yf = floorf(y);
      const int x0 = (int)xf, y0 = (int)yf;
      const float wx = x - xf, wy = y - yf;
      const size_t base = ((size_t)bc * CC + c) * (HFF * WFF);
      const bool vx0 = (x0 >= 0) & (x0 < WFF);
      const bool vx1 = (x0 + 1 >= 0) & (x0 + 1 < WFF);
      const bool vy0 = (y0 >= 0) & (y0 < HFF);
      const bool vy1 = (y0 + 1 >= 0) & (y0 + 1 < HFF);
      if (vy0) {
        const size_t rb = base + (size_t)y0 * WFF;
        if (vx0) acc += (1.f - wx) * (1.f - wy) * ldf1(feat, rb + x0, df);
        if (vx1) acc += wx * (1.f - wy) * ldf1(feat, rb + x0 + 1, df);
      }
      if (vy1) {
        const size_t rb = base + (size_t)(y0 + 1) * WFF;
        if (vx0) acc += (1.f - wx) * wy * ldf1(feat, rb + x0, df);
        if (vx1) acc += wx * wy * ldf1(feat, rb + x0 + 1, df);
      }
    }
    S[((size_t)q * BB + b) * CC + c] = f2bf(acc * (1.f / 6.f));
  }
}

// ============================================================
extern "C" void kernel_launch(void* const* d_in, const int* in_sizes, int n_in,
                              void* d_out, int out_size, void* d_ws, size_t ws_size,
                              hipStream_t stream) {
  (void)in_sizes; (void)n_in; (void)out_size; (void)ws_size;
  char* base = (char*)d_ws;
  int* flag = (int*)base;
  float* UV = (float*)(base + WB_UV);
  u16* WQKV = (u16*)(base + WB_WQKV);
  u16* WOP  = (u16*)(base + WB_WOP);
  u16* WSC  = (u16*)(base + WB_WSC);
  u16* WF1  = (u16*)(base + WB_WF1);
  u16* WF2  = (u16*)(base + WB_WF2);
  u16* S1 = (u16*)(base + WB_S1);
  u16* S2 = (u16*)(base + WB_S2);
  u16* S3 = (u16*)(base + WB_S3);
  u16* VT = (u16*)(base + WB_VT);
  u16* H  = (u16*)(base + WB_H);

  detect_k<<<1, 64, 0, stream>>>((const u16*)d_in[3], flag);

  WDesc wd;
  wd.src[0] = d_in[7];  wd.dst[0] = WQKV; wd.n[0] = 49152;
  wd.src[1] = d_in[9];  wd.dst[1] = WOP;  wd.n[1] = 16384;
  wd.src[2] = d_in[13]; wd.dst[2] = WSC;  wd.n[2] = 16384;
  cvtw_k<<<dim3(128, 5), 256, 0, stream>>>(wd, VT, d_in[3], d_in[4], d_in[5], UV, flag);
  trans_k<<<dim3(64, 2), 256, 0, stream>>>(d_in[17], WF1, d_in[19], WF2, flag);

  // Fused QKV projections (32 rows/wave): Q->S1, K->S2, V->VT (perm store)
  gemm_qkv<<<dim3(157, 12), 64, 0, stream>>>(d_in[0], d_in[1], WQKV, d_in[8], S1, S2, VT, flag);

  attn_mf<<<dim3(79, 16), 256, 0, stream>>>(S1, S2, VT, S3);

  // out-proj (+bevq residual) + LN1 -> S2
  gemm_ln<256,2,0><<<313, 256, 0, stream>>>(S3, WOP, d_in[10], d_in[0], d_in[11], d_in[12], S2, MROWS, flag);

  // sampling -> VT slot (dead after attn)
  samp_k<<<dim3(CC, BB * 5), 256, 0, stream>>>(d_in[2], UV, VT, flag);

  // SCA (+S2 residual) + LN2 -> S1
  gemm_ln<256,1,0><<<313, 256, 0, stream>>>(VT, WSC, d_in[14], S2, d_in[15], d_in[16], S1, MROWS, flag);

  // FFN: gelu(S1 @ W1 + b1) -> H ; (H @ W2 + b2 + S1) + LN3 -> out
  gemm_nl<256,1,4><<<dim3(157, 16), 64, 0, stream>>>(S1, WF1, d_in[18], H, MROWS, DFF, flag);
  gemm_ln<1024,1,1><<<313, 256, 0, stream>>>(H, WF2, d_in[20], S1, d_in[21], d_in[22], d_out, MROWS, flag);
}

// Round 12
// 453.938 us; speedup vs baseline: 1.0474x; 1.0103x over previous
//
#include <hip/hip_runtime.h>

typedef unsigned short u16;
typedef __attribute__((ext_vector_type(8))) __bf16 bf8_t;
typedef __attribute__((ext_vector_type(4))) float f4_t;

union bf8u { u16 u[8]; bf8_t v; uint4 q; };

// ---------- bf16 helpers ----------
__device__ __forceinline__ float bf2f(u16 v) {
  return __uint_as_float(((unsigned int)v) << 16);
}
__device__ __forceinline__ u16 f2bf(float f) {
  union { __bf16 h; u16 u; } c;          // gfx950: single v_cvt_pk_bf16_f32 (RNE)
  c.h = (__bf16)f;
  return c.u;
}
__device__ __forceinline__ float bflo(unsigned int w) { return __uint_as_float(w << 16); }
__device__ __forceinline__ float bfhi(unsigned int w) { return __uint_as_float(w & 0xFFFF0000u); }
__device__ __forceinline__ float ldf1(const void* p, size_t i, int isf32) {
  return isf32 ? ((const float*)p)[i] : bf2f(((const u16*)p)[i]);
}
// packed f32x2 -> bf16x2 (RNE), single HW instr
__device__ __forceinline__ unsigned int cvtpk(float lo, float hi) {
  unsigned int w;
  asm("v_cvt_pk_bf16_f32 %0, %1, %2" : "=v"(w) : "v"(lo), "v"(hi));
  return w;
}

// ---------- sizes ----------
#define LQ    2500
#define LQP   2560      /* padded token count for Vt */
#define BB    2
#define CC    256
#define NCC   6
#define HFF   64
#define WFF   176
#define DFF   1024
#define MROWS 5000

// ---------- workspace byte offsets (end < 20.7MB proven-safe) ----------
#define WB_UV   256
#define WB_WQKV 240256
#define WB_WOP  633472
#define WB_WSC  764544
#define WB_WF1  895616
#define WB_WF2  1419904
#define WB_S1   1944192                 /* 2,621,440 each */
#define WB_S2   (WB_S1 + 2621440)
#define WB_S3   (WB_S2 + 2621440)
#define WB_VT   (WB_S3 + 2621440)       /* 512 x 2560 x 2B */
#define WB_H    WB_S2                   /* overlaps S2,S3,VT (dead at FFN time) */

// ============================================================
__global__ void detect_k(const u16* __restrict__ rp, int* __restrict__ flag) {
  int bad = 0;
  for (int i = threadIdx.x; i < 7500; i += 64) {
    float v = bf2f(rp[i]);
    if (!(fabsf(v) < 1e6f)) bad = 1;
  }
  int anybad = __any(bad);
  if (threadIdx.x == 0) flag[0] = anybad ? 1 : 0;   // 1 = f32, 0 = bf16
}

// ============================================================
// prep: vectorized weight convert / Vt pad / uv projection.
//   y in [0,2]: x4 convert; y==3: Vt zero pad; y==4: uv.
// ============================================================
struct WDesc {
  const void* src[3];
  u16* dst[3];
  int n[3];
};
__global__ __launch_bounds__(256) void cvtw_k(WDesc d, u16* __restrict__ vtp,
    const void* __restrict__ refp, const void* __restrict__ intr,
    const void* __restrict__ extr, float* __restrict__ uv,
    const int* __restrict__ flag) {
  const int df = flag[0];
  const int i = blockIdx.y;
  if (i == 4) {                          // uv projection task
    for (int idx = blockIdx.x * 256 + threadIdx.x; idx < BB * NCC * LQ; idx += gridDim.x * 256) {
      const int bc = idx / LQ;
      const int q = idx - bc * LQ;
      float R[3][3], tv[3], Kc[3][3], p[3];
#pragma unroll
      for (int a = 0; a < 3; ++a) {
#pragma unroll
        for (int j = 0; j < 3; ++j) {
          R[a][j] = ldf1(extr, bc*16 + a*4 + j, df);
          Kc[a][j] = ldf1(intr, bc*9 + a*3 + j, df);
        }
        tv[a] = ldf1(extr, bc*16 + a*4 + 3, df);
      }
#pragma unroll
      for (int j = 0; j < 3; ++j) p[j] = ldf1(refp, q*3 + j, df) - tv[j];
      float pc[3];
#pragma unroll
      for (int a = 0; a < 3; ++a) pc[a] = R[0][a]*p[0] + R[1][a]*p[1] + R[2][a]*p[2];
      float im[3];
#pragma unroll
      for (int a = 0; a < 3; ++a) im[a] = Kc[a][0]*pc[0] + Kc[a][1]*pc[1] + Kc[a][2]*pc[2];
      const float z = fmaxf(im[2], 1e-5f);
      uv[(size_t)idx*2 + 0] = im[0] / z - 0.5f;
      uv[(size_t)idx*2 + 1] = im[1] / z - 0.5f;
    }
    return;
  }
  if (i == 3) {                          // Vt zero pad
    const int n = 512 * (LQP - LQ);
    for (int j = blockIdx.x * 256 + threadIdx.x; j < n; j += gridDim.x * 256) {
      const int row = j / (LQP - LQ), col = LQ + j % (LQP - LQ);
      vtp[(size_t)row * LQP + col] = 0;
    }
    return;
  }
  const int n = d.n[i];
  for (int j = blockIdx.x * 256 + threadIdx.x; j < n; j += gridDim.x * 256) {
    if (df) {
      const float4 r = ((const float4*)d.src[i])[j];
      const unsigned int lo = (unsigned int)f2bf(r.x) | ((unsigned int)f2bf(r.y) << 16);
      const unsigned int hi = (unsigned int)f2bf(r.z) | ((unsigned int)f2bf(r.w) << 16);
      ((uint2*)d.dst[i])[j] = make_uint2(lo, hi);
    } else {
      ((uint2*)d.dst[i])[j] = ((const uint2*)d.src[i])[j];
    }
  }
}

// ============================================================
// LDS-tiled transpose-convert for the two FFN weights (R10-proven).
// ============================================================
__global__ __launch_bounds__(256) void trans_k(
    const void* __restrict__ s0, u16* __restrict__ d0,
    const void* __restrict__ s1, u16* __restrict__ d1,
    const int* __restrict__ flag)
{
  __shared__ u16 tile[64][66];
  const int df = flag[0];
  const void* src; u16* dst; int Ks, Ns;
  if (blockIdx.y == 0) { src = s0; dst = d0; Ks = 256;  Ns = 1024; }
  else                 { src = s1; dst = d1; Ks = 1024; Ns = 256;  }
  const int ntn = Ns >> 6;
  const int kx = blockIdx.x / ntn, nx = blockIdx.x % ntn;
  const int k0 = kx * 64, n0 = nx * 64;
  const int t = threadIdx.x;
  const int col = t & 63, rq = t >> 6;
#pragma unroll
  for (int i = 0; i < 16; ++i) {
    const int r = i * 4 + rq;
    tile[col][r] = f2bf(ldf1(src, (size_t)(k0 + r) * Ns + n0 + col, df));
  }
  __syncthreads();
#pragma unroll
  for (int i = 0; i < 16; ++i) {
    const int n = i * 4 + rq;
    dst[(size_t)(n0 + n) * Ks + k0 + col] = tile[n][col];
  }
}

// ============================================================
// No-LDS MFMA GEMM, one wave computes 32M x (NT*16)N: two A-row
// groups share every B fragment (R8/R11-proven).  FFN1 only.
// ============================================================
template<int KTPL, int ACT, int NT>
__global__ __launch_bounds__(64) void gemm_nl(
    const u16* __restrict__ Xv, const u16* __restrict__ W,
    const void* __restrict__ bias,
    u16* __restrict__ Y, int M, int N, const int* __restrict__ flag)
{
  const int df = flag[0];
  const int lane = threadIdx.x;
  const int ln15 = lane & 15, l4 = lane >> 4;
  const int m0 = blockIdx.x * 32, n0 = blockIdx.y * (NT * 16);
  const int am0 = min(m0 + ln15, M - 1);
  const int am1 = min(m0 + 16 + ln15, M - 1);

  f4_t acc[2][NT];
#pragma unroll
  for (int g = 0; g < 2; ++g)
#pragma unroll
    for (int nt = 0; nt < NT; ++nt) acc[g][nt] = (f4_t){0.f, 0.f, 0.f, 0.f};

#pragma unroll 8
  for (int k0 = 0; k0 < KTPL; k0 += 32) {
    bf8u a0, a1;
    a0.q = *(const uint4*)(Xv + (size_t)am0 * KTPL + k0 + l4 * 8);
    a1.q = *(const uint4*)(Xv + (size_t)am1 * KTPL + k0 + l4 * 8);
#pragma unroll
    for (int nt = 0; nt < NT; ++nt) {
      bf8u b;
      b.q = *(const uint4*)&W[(size_t)(n0 + nt * 16 + ln15) * KTPL + k0 + l4 * 8];
      acc[0][nt] = __builtin_amdgcn_mfma_f32_16x16x32_bf16(a0.v, b.v, acc[0][nt], 0, 0, 0);
      acc[1][nt] = __builtin_amdgcn_mfma_f32_16x16x32_bf16(a1.v, b.v, acc[1][nt], 0, 0, 0);
    }
  }
#pragma unroll
  for (int g = 0; g < 2; ++g) {
#pragma unroll
    for (int nt = 0; nt < NT; ++nt) {
      const int gn = n0 + nt * 16 + ln15;
      const float bv = ldf1(bias, gn, df);
#pragma unroll
      for (int r = 0; r < 4; ++r) {
        const int gm = m0 + g * 16 + l4 * 4 + r;
        if (gm < M) {
          float x = acc[g][nt][r] + bv;
          if (ACT) x = 0.5f * x * (1.f + erff(x * 0.70710678118654752f));
          Y[(size_t)gm * N + gn] = f2bf(x);
        }
      }
    }
  }
}

// ============================================================
// GEMM (N=256) + residual + LayerNorm fused, 32 rows per block.
//   4 waves; wave wn owns cols wn*64 + nt*16 + ln15 for TWO 16-row
//   groups sharing every B fragment (2 A + 4 B loads per 8 MFMAs —
//   halves B-load count vs the 16-row version).  LN per group via
//   16-lane shuffles + sR[4][32] cross-wave LDS (R8-proven pattern).
// ============================================================
template<int KT, int RES, int TOOUT>
__global__ __launch_bounds__(256) void gemm_ln(
    const u16* __restrict__ Xv, const u16* __restrict__ W,
    const void* __restrict__ bias, const void* __restrict__ resv,
    const void* __restrict__ gw, const void* __restrict__ bw,
    void* __restrict__ Yv, int M, const int* __restrict__ flag)
{
  __shared__ float sR[4][32];
  const int df = flag[0];
  const int t = threadIdx.x;
  const int lane = t & 63, wn = t >> 6;
  const int ln15 = lane & 15, l4 = lane >> 4;
  const int m0 = blockIdx.x * 32;
  const int am0 = min(m0 + ln15, M - 1);
  const int am1 = min(m0 + 16 + ln15, M - 1);

  f4_t acc[2][4];
#pragma unroll
  for (int g = 0; g < 2; ++g)
#pragma unroll
    for (int nt = 0; nt < 4; ++nt) acc[g][nt] = (f4_t){0.f, 0.f, 0.f, 0.f};

#pragma unroll 8
  for (int k0 = 0; k0 < KT; k0 += 32) {
    bf8u a0, a1;
    a0.q = *(const uint4*)(Xv + (size_t)am0 * KT + k0 + l4 * 8);
    a1.q = *(const uint4*)(Xv + (size_t)am1 * KT + k0 + l4 * 8);
#pragma unroll
    for (int nt = 0; nt < 4; ++nt) {
      bf8u b;
      b.q = *(const uint4*)&W[(size_t)(wn * 64 + nt * 16 + ln15) * KT + k0 + l4 * 8];
      acc[0][nt] = __builtin_amdgcn_mfma_f32_16x16x32_bf16(a0.v, b.v, acc[0][nt], 0, 0, 0);
      acc[1][nt] = __builtin_amdgcn_mfma_f32_16x16x32_bf16(a1.v, b.v, acc[1][nt], 0, 0, 0);
    }
  }
  // ---- x = acc + bias + residual ----
  float x[2][4][4];
#pragma unroll
  for (int g = 0; g < 2; ++g)
#pragma unroll
    for (int nt = 0; nt < 4; ++nt) {
      const int gn = wn * 64 + nt * 16 + ln15;
      const float bv = ldf1(bias, gn, df);
#pragma unroll
      for (int r = 0; r < 4; ++r) {
        const int gm = m0 + g * 16 + l4 * 4 + r;
        float xx = acc[g][nt][r] + bv;
        const size_t ri = (size_t)min(gm, M - 1) * CC + gn;
        if (RES == 1)      xx += bf2f(((const u16*)resv)[ri]);
        else if (RES == 2) xx += ldf1(resv, ri, df);
        x[g][nt][r] = xx;
      }
    }
  // ---- pass 1: row mean ----
#pragma unroll
  for (int g = 0; g < 2; ++g) {
    float ps[4];
#pragma unroll
    for (int r = 0; r < 4; ++r) {
      ps[r] = x[g][0][r] + x[g][1][r] + x[g][2][r] + x[g][3][r];
#pragma unroll
      for (int o = 1; o < 16; o <<= 1) ps[r] += __shfl_xor(ps[r], o);
    }
    if (ln15 == 0) {
#pragma unroll
      for (int r = 0; r < 4; ++r) sR[wn][g * 16 + l4 * 4 + r] = ps[r];
    }
  }
  __syncthreads();
  float mean[2][4];
#pragma unroll
  for (int g = 0; g < 2; ++g)
#pragma unroll
    for (int r = 0; r < 4; ++r) {
      const int row = g * 16 + l4 * 4 + r;
      mean[g][r] = (sR[0][row] + sR[1][row] + sR[2][row] + sR[3][row]) * 0.00390625f;
    }
  __syncthreads();
  // ---- pass 2: row variance ----
#pragma unroll
  for (int g = 0; g < 2; ++g) {
    float pq[4];
#pragma unroll
    for (int r = 0; r < 4; ++r) {
      float d0 = x[g][0][r] - mean[g][r], d1 = x[g][1][r] - mean[g][r];
      float d2 = x[g][2][r] - mean[g][r], d3 = x[g][3][r] - mean[g][r];
      pq[r] = d0*d0 + d1*d1 + d2*d2 + d3*d3;
#pragma unroll
      for (int o = 1; o < 16; o <<= 1) pq[r] += __shfl_xor(pq[r], o);
    }
    if (ln15 == 0) {
#pragma unroll
      for (int r = 0; r < 4; ++r) sR[wn][g * 16 + l4 * 4 + r] = pq[r];
    }
  }
  __syncthreads();
  float rstd[2][4];
#pragma unroll
  for (int g = 0; g < 2; ++g)
#pragma unroll
    for (int r = 0; r < 4; ++r) {
      const int row = g * 16 + l4 * 4 + r;
      const float v = (sR[0][row] + sR[1][row] + sR[2][row] + sR[3][row]) * 0.00390625f;
      rstd[g][r] = rsqrtf(v + 1e-5f);
    }
  // ---- normalize + write ----
#pragma unroll
  for (int g = 0; g < 2; ++g)
#pragma unroll
    for (int nt = 0; nt < 4; ++nt) {
      const int gn = wn * 64 + nt * 16 + ln15;
      const float gg = ldf1(gw, gn, df);
      const float be = ldf1(bw, gn, df);
#pragma unroll
      for (int r = 0; r < 4; ++r) {
        const int gm = m0 + g * 16 + l4 * 4 + r;
        if (gm < M) {
          const float y = (x[g][nt][r] - mean[g][r]) * rstd[g][r] * gg + be;
          if (TOOUT && df) ((float*)Yv)[(size_t)gm * CC + gn] = y;
          else             ((u16*)Yv)[(size_t)gm * CC + gn] = f2bf(y);
        }
      }
    }
}

// ============================================================
// Fused QKV projection, 32 M-rows per wave (shared B fragments).
// grid (157, 12): y>>2 = {Q,K,V}, y&3 = 64-col tile.
// ============================================================
__global__ __launch_bounds__(64) void gemm_qkv(
    const void* __restrict__ Xq, const void* __restrict__ Xkv,
    const u16* __restrict__ Wqkv, const void* __restrict__ bias,
    u16* __restrict__ Qo, u16* __restrict__ Ko, u16* __restrict__ Vt,
    const int* __restrict__ flag)
{
  const int df = flag[0];
  const int lane = threadIdx.x;
  const int ln15 = lane & 15, l4 = lane >> 4;
  const int which = blockIdx.y >> 2;
  const int n0 = (blockIdx.y & 3) * 64;
  const void* Xv = (which == 0) ? Xq : Xkv;
  const u16* W = Wqkv + (size_t)which * 65536;
  const int m0 = blockIdx.x * 32;
  const int am0 = min(m0 + ln15, MROWS - 1);
  const int am1 = min(m0 + 16 + ln15, MROWS - 1);

  f4_t acc[2][4];
#pragma unroll
  for (int g = 0; g < 2; ++g)
#pragma unroll
    for (int nt = 0; nt < 4; ++nt) acc[g][nt] = (f4_t){0.f, 0.f, 0.f, 0.f};

#pragma unroll 8
  for (int k0 = 0; k0 < CC; k0 += 32) {
    bf8u a0, a1;
    if (df) {
      const float* p0 = (const float*)Xv + (size_t)am0 * CC + k0 + l4 * 8;
      float4 r0 = *(const float4*)p0, r1 = *(const float4*)(p0 + 4);
      a0.u[0]=f2bf(r0.x); a0.u[1]=f2bf(r0.y); a0.u[2]=f2bf(r0.z); a0.u[3]=f2bf(r0.w);
      a0.u[4]=f2bf(r1.x); a0.u[5]=f2bf(r1.y); a0.u[6]=f2bf(r1.z); a0.u[7]=f2bf(r1.w);
      const float* p1 = (const float*)Xv + (size_t)am1 * CC + k0 + l4 * 8;
      float4 r2 = *(const float4*)p1, r3 = *(const float4*)(p1 + 4);
      a1.u[0]=f2bf(r2.x); a1.u[1]=f2bf(r2.y); a1.u[2]=f2bf(r2.z); a1.u[3]=f2bf(r2.w);
      a1.u[4]=f2bf(r3.x); a1.u[5]=f2bf(r3.y); a1.u[6]=f2bf(r3.z); a1.u[7]=f2bf(r3.w);
    } else {
      a0.q = *(const uint4*)((const u16*)Xv + (size_t)am0 * CC + k0 + l4 * 8);
      a1.q = *(const uint4*)((const u16*)Xv + (size_t)am1 * CC + k0 + l4 * 8);
    }
#pragma unroll
    for (int nt = 0; nt < 4; ++nt) {
      bf8u b;
      b.q = *(const uint4*)&W[(size_t)(n0 + nt * 16 + ln15) * CC + k0 + l4 * 8];
      acc[0][nt] = __builtin_amdgcn_mfma_f32_16x16x32_bf16(a0.v, b.v, acc[0][nt], 0, 0, 0);
      acc[1][nt] = __builtin_amdgcn_mfma_f32_16x16x32_bf16(a1.v, b.v, acc[1][nt], 0, 0, 0);
    }
  }
#pragma unroll
  for (int g = 0; g < 2; ++g) {
#pragma unroll
    for (int nt = 0; nt < 4; ++nt) {
      const int gn = n0 + nt * 16 + ln15;
      const float bv = ldf1(bias, which * 256 + gn, df);
#pragma unroll
      for (int r = 0; r < 4; ++r) {
        const int gm = m0 + g * 16 + l4 * 4 + r;
        if (gm < MROWS) {
          const float x = acc[g][nt][r] + bv;
          if (which == 2) {
            const int tt = gm >> 1;
            const int tx = tt & 63;
            const int tp = (tx & 35) | ((tx & 12) << 1) | ((tx & 16) >> 2);
            Vt[(size_t)(gn + (gm & 1) * 256) * LQP + ((tt & ~63) | tp)] = f2bf(x);
          } else {
            u16* Y = (which == 0) ? Qo : Ko;
            Y[(size_t)gm * CC + gn] = f2bf(x);
          }
        }
      }
    }
  }
}

// ============================================================
// Split-K flash attention, swapped-operand + register-resident P,
// 32 q per wave (R8-proven: halved load/miss count, -40us).
// ============================================================
#define TPW 10
__global__ __launch_bounds__(256) void attn_mf(
    const u16* __restrict__ Qw, const u16* __restrict__ Kw,
    const u16* __restrict__ Vt, u16* __restrict__ Ow)
{
  __shared__ float sO[4][32][33];                // [wave][q][32 d + pad]
  __shared__ float sM[4][32];
  __shared__ float sL[4][32];
  const int t = threadIdx.x;
  const int lane = t & 63, w = t >> 6;
  const int ln15 = lane & 15, l4 = lane >> 4;
  const int q0 = blockIdx.x * 32;
  const int by = blockIdx.y;           // b*8+h
  const int b = by >> 3, h = by & 7;
  const float SCL2E = 0.25505654481f;  // (1/sqrt(32)) * log2(e)

  bf8u aqA, aqB;
  {
    const int qra = min(q0 + ln15, LQ - 1);
    const int qrb = min(q0 + 16 + ln15, LQ - 1);
    bf8u qr;
    qr.q = *(const uint4*)&Qw[((size_t)qra * BB + b) * CC + h * 32 + l4 * 8];
#pragma unroll
    for (int i = 0; i < 8; ++i) aqA.u[i] = f2bf(bf2f(qr.u[i]) * SCL2E);
    qr.q = *(const uint4*)&Qw[((size_t)qrb * BB + b) * CC + h * 32 + l4 * 8];
#pragma unroll
    for (int i = 0; i < 8; ++i) aqB.u[i] = f2bf(bf2f(qr.u[i]) * SCL2E);
  }

  f4_t oaccA[2], oaccB[2];
  oaccA[0] = (f4_t){0.f,0.f,0.f,0.f}; oaccA[1] = (f4_t){0.f,0.f,0.f,0.f};
  oaccB[0] = (f4_t){0.f,0.f,0.f,0.f}; oaccB[1] = (f4_t){0.f,0.f,0.f,0.f};
  float mA = -1e30f, lA = 0.f;
  float mB = -1e30f, lB = 0.f;

  const int kt0 = w * TPW;
  const u16* Kbase = &Kw[(size_t)b * CC + h * 32 + l4 * 8];
  const u16* Vbase = &Vt[(size_t)(by * 32 + ln15) * LQP + l4 * 8];

  // ---- prefetch K for first tile ----
  bf8u bkn[4];
#pragma unroll
  for (int nt = 0; nt < 4; ++nt)
    bkn[nt].q = *(const uint4*)&Kbase[(size_t)(kt0 * 64 + nt * 16 + ln15) * CC];

  for (int kt = kt0; kt < kt0 + TPW; ++kt) {
    const int kb = kt * 64;
    // ---- Vt loads (consumed last): latency hides under QK+softmax ----
    bf8u av[2][2];
#pragma unroll
    for (int m = 0; m < 2; ++m)
#pragma unroll
      for (int dt = 0; dt < 2; ++dt)
        av[m][dt].q = *(const uint4*)&Vbase[(size_t)(dt * 16) * LQP + kb + m * 32];
    // ---- QK for both q-groups from the shared K fragments ----
    f4_t svA[4], svB[4];
    __builtin_amdgcn_s_setprio(1);
#pragma unroll
    for (int nt = 0; nt < 4; ++nt) {
      f4_t z = (f4_t){0.f,0.f,0.f,0.f};
      svA[nt] = __builtin_amdgcn_mfma_f32_16x16x32_bf16(bkn[nt].v, aqA.v, z, 0, 0, 0);
      f4_t z2 = (f4_t){0.f,0.f,0.f,0.f};
      svB[nt] = __builtin_amdgcn_mfma_f32_16x16x32_bf16(bkn[nt].v, aqB.v, z2, 0, 0, 0);
    }
    __builtin_amdgcn_s_setprio(0);
    // ---- issue next tile's K loads ----
    if (kt + 1 < kt0 + TPW) {
#pragma unroll
      for (int nt = 0; nt < 4; ++nt)
        bkn[nt].q = *(const uint4*)&Kbase[(size_t)(kb + 64 + nt * 16 + ln15) * CC];
    }
    float pA[4][4], pB[4][4];
    if (kb + 64 <= LQ) {
#pragma unroll
      for (int nt = 0; nt < 4; ++nt)
#pragma unroll
        for (int r = 0; r < 4; ++r) { pA[nt][r] = svA[nt][r]; pB[nt][r] = svB[nt][r]; }
    } else {
#pragma unroll
      for (int nt = 0; nt < 4; ++nt)
#pragma unroll
        for (int r = 0; r < 4; ++r) {
          const bool ok = (kb + nt * 16 + l4 * 4 + r < LQ);
          pA[nt][r] = ok ? svA[nt][r] : -1e30f;
          pB[nt][r] = ok ? svB[nt][r] : -1e30f;
        }
    }
    // ---- group A softmax ----
    {
      const float thr = mA + 8.f;
      bool nd = false;
#pragma unroll
      for (int nt = 0; nt < 4; ++nt)
#pragma unroll
        for (int r = 0; r < 4; ++r) nd |= (pA[nt][r] > thr);
      if (__any(nd)) {
        const float x0 = fmaxf(fmaxf(pA[0][0], pA[0][1]), fmaxf(pA[0][2], pA[0][3]));
        const float x1 = fmaxf(fmaxf(pA[1][0], pA[1][1]), fmaxf(pA[1][2], pA[1][3]));
        const float x2 = fmaxf(fmaxf(pA[2][0], pA[2][1]), fmaxf(pA[2][2], pA[2][3]));
        const float x3 = fmaxf(fmaxf(pA[3][0], pA[3][1]), fmaxf(pA[3][2], pA[3][3]));
        float mloc = fmaxf(fmaxf(x0, x1), fmaxf(x2, x3));
        mloc = fmaxf(mloc, __shfl_xor(mloc, 16));
        mloc = fmaxf(mloc, __shfl_xor(mloc, 32));
        const float mn = fmaxf(mA, mloc);
        const float alpha = __builtin_amdgcn_exp2f(mA - mn);
        mA = mn;
        lA *= alpha;
#pragma unroll
        for (int r = 0; r < 4; ++r) { oaccA[0][r] *= alpha; oaccA[1][r] *= alpha; }
      }
      float s = 0.f;
#pragma unroll
      for (int nt = 0; nt < 4; ++nt)
#pragma unroll
        for (int r = 0; r < 4; ++r) {
          const float e = __builtin_amdgcn_exp2f(pA[nt][r] - mA);
          pA[nt][r] = e; s += e;
        }
      lA += s;
    }
    // ---- group B softmax ----
    {
      const float thr = mB + 8.f;
      bool nd = false;
#pragma unroll
      for (int nt = 0; nt < 4; ++nt)
#pragma unroll
        for (int r = 0; r < 4; ++r) nd |= (pB[nt][r] > thr);
      if (__any(nd)) {
        const float x0 = fmaxf(fmaxf(pB[0][0], pB[0][1]), fmaxf(pB[0][2], pB[0][3]));
        const float x1 = fmaxf(fmaxf(pB[1][0], pB[1][1]), fmaxf(pB[1][2], pB[1][3]));
        const float x2 = fmaxf(fmaxf(pB[2][0], pB[2][1]), fmaxf(pB[2][2], pB[2][3]));
        const float x3 = fmaxf(fmaxf(pB[3][0], pB[3][1]), fmaxf(pB[3][2], pB[3][3]));
        float mloc = fmaxf(fmaxf(x0, x1), fmaxf(x2, x3));
        mloc = fmaxf(mloc, __shfl_xor(mloc, 16));
        mloc = fmaxf(mloc, __shfl_xor(mloc, 32));
        const float mn = fmaxf(mB, mloc);
        const float alpha = __builtin_amdgcn_exp2f(mB - mn);
        mB = mn;
        lB *= alpha;
#pragma unroll
        for (int r = 0; r < 4; ++r) { oaccB[0][r] *= alpha; oaccB[1][r] *= alpha; }
      }
      float s = 0.f;
#pragma unroll
      for (int nt = 0; nt < 4; ++nt)
#pragma unroll
        for (int r = 0; r < 4; ++r) {
          const float e = __builtin_amdgcn_exp2f(pB[nt][r] - mB);
          pB[nt][r] = e; s += e;
        }
      lB += s;
    }
    // ---- PV: both groups share av fragments ----
    __builtin_amdgcn_s_setprio(1);
#pragma unroll
    for (int m = 0; m < 2; ++m) {
      bf8u pba, pbb;                   // slot i -> key (2m+(i>>2))*16 + l4*4 + (i&3)
      pba.q = make_uint4(cvtpk(pA[2*m][0], pA[2*m][1]),   cvtpk(pA[2*m][2], pA[2*m][3]),
                         cvtpk(pA[2*m+1][0], pA[2*m+1][1]), cvtpk(pA[2*m+1][2], pA[2*m+1][3]));
      pbb.q = make_uint4(cvtpk(pB[2*m][0], pB[2*m][1]),   cvtpk(pB[2*m][2], pB[2*m][3]),
                         cvtpk(pB[2*m+1][0], pB[2*m+1][1]), cvtpk(pB[2*m+1][2], pB[2*m+1][3]));
#pragma unroll
      for (int dt = 0; dt < 2; ++dt) {
        oaccA[dt] = __builtin_amdgcn_mfma_f32_16x16x32_bf16(av[m][dt].v, pba.v, oaccA[dt], 0, 0, 0);
        oaccB[dt] = __builtin_amdgcn_mfma_f32_16x16x32_bf16(av[m][dt].v, pbb.v, oaccB[dt], 0, 0, 0);
      }
    }
    __builtin_amdgcn_s_setprio(0);
  }
  // ---- reduce l across the 4 l4-lanes of each q (consistent scaling) ----
  lA += __shfl_xor(lA, 16);  lA += __shfl_xor(lA, 32);
  lB += __shfl_xor(lB, 16);  lB += __shfl_xor(lB, 32);
  // ---- write partials, merge in LDS ----
#pragma unroll
  for (int dt = 0; dt < 2; ++dt)
#pragma unroll
    for (int r = 0; r < 4; ++r) {
      sO[w][ln15][dt * 16 + l4 * 4 + r]      = oaccA[dt][r];
      sO[w][16 + ln15][dt * 16 + l4 * 4 + r] = oaccB[dt][r];
    }
  if (l4 == 0) {
    sM[w][ln15] = mA; sL[w][ln15] = lA;
    sM[w][16 + ln15] = mB; sL[w][16 + ln15] = lB;
  }
  __syncthreads();
#pragma unroll
  for (int i = t; i < 1024; i += 256) {
    const int row = i >> 5, col = i & 31;
    const float M = fmaxf(fmaxf(sM[0][row], sM[1][row]), fmaxf(sM[2][row], sM[3][row]));
    float l = 0.f, O = 0.f;
#pragma unroll
    for (int w4 = 0; w4 < 4; ++w4) {
      const float sc = __builtin_amdgcn_exp2f(sM[w4][row] - M);
      l += sc * sL[w4][row];
      O += sc * sO[w4][row][col];
    }
    const int q = q0 + row;
    if (q < LQ)
      Ow[((size_t)q * BB + b) * CC + h * 32 + col] = f2bf(O / l);
  }
}

// ============================================================
// Grid-sample (R0-R4 proven version).
// ============================================================
__global__ __launch_bounds__(256) void samp_k(
    const void* __restrict__ feat, const float* __restrict__ uv,
    u16* __restrict__ S, const int* __restrict__ flag)
{
  const int df = flag[0];
  const int c = blockIdx.x;
  const int b = blockIdx.y / 5;
  const int ch = blockIdx.y % 5;
  const int qend = min((ch + 1) * 500, LQ);
  for (int q = ch * 500 + threadIdx.x; q < qend; q += 256) {
    float acc = 0.f;
#pragma unroll
    for (int cam = 0; cam < NCC; ++cam) {
      const int bc = b * NCC + cam;
      const float x = uv[((size_t)bc * LQ + q) * 2 + 0];
      const float y = uv[((size_t)bc * LQ + q) * 2 + 1];
      const float xf = floorf(x), yf = floorf(y);
      const int x0 = (int)xf, y0 = (int)yf;
      const float wx = x - xf, wy = y - yf;
      const size_t base = ((size_t)bc * CC + c) * (HFF * WFF);
      const bool vx0 = (x0 >= 0) & (x0 < WFF);
      const bool vx1 = (x0 + 1 >= 0) & (x0 + 1 < WFF);
      const bool vy0 = (y0 >= 0) & (y0 < HFF);
      const bool vy1 = (y0 + 1 >= 0) & (y0 + 1 < HFF);
      if (vy0) {
        const size_t rb = base + (size_t)y0 * WFF;
        if (vx0) acc += (1.f - wx) * (1.f - wy) * ldf1(feat, rb + x0, df);
        if (vx1) acc += wx * (1.f - wy) * ldf1(feat, rb + x0 + 1, df);
      }
      if (vy1) {
        const size_t rb = base + (size_t)(y0 + 1) * WFF;
        if (vx0) acc += (1.f - wx) * wy * ldf1(feat, rb + x0, df);
        if (vx1) acc += wx * wy * ldf1(feat, rb + x0 + 1, df);
      }
    }
    S[((size_t)q * BB + b) * CC + c] = f2bf(acc * (1.f / 6.f));
  }
}

// ============================================================
extern "C" void kernel_launch(void* const* d_in, const int* in_sizes, int n_in,
                              void* d_out, int out_size, void* d_ws, size_t ws_size,
                              hipStream_t stream) {
  (void)in_sizes; (void)n_in; (void)out_size; (void)ws_size;
  char* base = (char*)d_ws;
  int* flag = (int*)base;
  float* UV = (float*)(base + WB_UV);
  u16* WQKV = (u16*)(base + WB_WQKV);
  u16* WOP  = (u16*)(base + WB_WOP);
  u16* WSC  = (u16*)(base + WB_WSC);
  u16* WF1  = (u16*)(base + WB_WF1);
  u16* WF2  = (u16*)(base + WB_WF2);
  u16* S1 = (u16*)(base + WB_S1);
  u16* S2 = (u16*)(base + WB_S2);
  u16* S3 = (u16*)(base + WB_S3);
  u16* VT = (u16*)(base + WB_VT);
  u16* H  = (u16*)(base + WB_H);

  detect_k<<<1, 64, 0, stream>>>((const u16*)d_in[3], flag);

  WDesc wd;
  wd.src[0] = d_in[7];  wd.dst[0] = WQKV; wd.n[0] = 49152;
  wd.src[1] = d_in[9];  wd.dst[1] = WOP;  wd.n[1] = 16384;
  wd.src[2] = d_in[13]; wd.dst[2] = WSC;  wd.n[2] = 16384;
  cvtw_k<<<dim3(128, 5), 256, 0, stream>>>(wd, VT, d_in[3], d_in[4], d_in[5], UV, flag);
  trans_k<<<dim3(64, 2), 256, 0, stream>>>(d_in[17], WF1, d_in[19], WF2, flag);

  // Fused QKV projections (32 rows/wave): Q->S1, K->S2, V->VT (perm store)
  gemm_qkv<<<dim3(157, 12), 64, 0, stream>>>(d_in[0], d_in[1], WQKV, d_in[8], S1, S2, VT, flag);

  attn_mf<<<dim3(79, 16), 256, 0, stream>>>(S1, S2, VT, S3);

  // out-proj (+bevq residual) + LN1 -> S2
  gemm_ln<256,2,0><<<157, 256, 0, stream>>>(S3, WOP, d_in[10], d_in[0], d_in[11], d_in[12], S2, MROWS, flag);

  // sampling -> VT slot (dead after attn)
  samp_k<<<dim3(CC, BB * 5), 256, 0, stream>>>(d_in[2], UV, VT, flag);

  // SCA (+S2 residual) + LN2 -> S1
  gemm_ln<256,1,0><<<157, 256, 0, stream>>>(VT, WSC, d_in[14], S2, d_in[15], d_in[16], S1, MROWS, flag);

  // FFN: gelu(S1 @ W1 + b1) -> H ; (H @ W2 + b2 + S1) + LN3 -> out
  gemm_nl<256,1,4><<<dim3(157, 16), 64, 0, stream>>>(S1, WF1, d_in[18], H, MROWS, DFF, flag);
  gemm_ln<1024,1,1><<<157, 256, 0, stream>>>(H, WF2, d_in[20], S1, d_in[21], d_in[22], d_out, MROWS, flag);
}